// Round 1
// baseline (1100.696 us; speedup 1.0000x reference)
//
#include <hip/hip_runtime.h>
#include <hip/hip_bf16.h>
#include <stdint.h>

// Problem constants (B,T,C,NH,LEVEL) = (2,2048,1024,16,3)
#define B_    2
#define T_    2048
#define CD    1024
#define NH_   16
#define HS_   64
#define NSETS 511        // sum_{l=3..11} 2048>>l
#define QKV_LD 3072

typedef __attribute__((ext_vector_type(8))) short  short8;
typedef __attribute__((ext_vector_type(4))) float  f32x4;

__device__ __forceinline__ unsigned short f2bf(float f) {
  unsigned u = __float_as_uint(f);
  unsigned r = 0x7FFFu + ((u >> 16) & 1u);   // round-to-nearest-even
  return (unsigned short)((u + r) >> 16);
}
__device__ __forceinline__ float bf2f(unsigned short h) {
  return __uint_as_float(((unsigned)h) << 16);
}
__device__ __forceinline__ float elu1(float x) {  // elu(x)+1
  return x > 0.f ? x + 1.f : __expf(x);
}

// ---------------- K1: f32 -> bf16 hi (+ optional lo residual) -------------
__global__ void split_kernel(const float* __restrict__ src,
                             unsigned short* __restrict__ hi,
                             unsigned short* __restrict__ lo, int n) {
  int i = blockIdx.x * 256 + threadIdx.x;
  if (i >= n) return;
  float v = src[i];
  unsigned short h = f2bf(v);
  hi[i] = h;
  if (lo) lo[i] = f2bf(v - bf2f(h));
}

// ---------------- K2/K7: C[M,N] = A[M,K] * B[N,K]^T  (bf16 MFMA) ----------
// SPLIT=1: A = Ah+Al, B = Bh+Bl; acc += Ah*Bh + Ah*Bl + Al*Bh  (~f32 precision)
// 128x128 tile, BK=32, 4 waves in 2x2 quadrants, 16x16x32 bf16 MFMA.
template<int SPLIT>
__global__ __launch_bounds__(256) void gemm_bt(
    const unsigned short* __restrict__ Ah, const unsigned short* __restrict__ Al,
    const unsigned short* __restrict__ Bh, const unsigned short* __restrict__ Bl,
    float* __restrict__ Cmat, int M, int N, int K)
{
  constexpr int NT = SPLIT ? 4 : 2;                  // tiles: Ah,Bh[,Al,Bl]
  __shared__ short lds[NT * 128 * 32];               // 8KB per tile

  const int row0 = blockIdx.y * 128;
  const int col0 = blockIdx.x * 128;
  const int tid  = threadIdx.x;
  const int lane = tid & 63;
  const int w    = tid >> 6;
  const int wr   = w >> 1, wc = w & 1;               // wave quadrant (64x64)

  f32x4 acc[4][4];
  #pragma unroll
  for (int a = 0; a < 4; ++a)
    #pragma unroll
    for (int b = 0; b < 4; ++b)
      acc[a][b] = (f32x4){0.f, 0.f, 0.f, 0.f};

  const int rlane = lane & 15;
  const int klane = (lane >> 4) * 8;

  for (int kt = 0; kt < K; kt += 32) {
    __syncthreads();
    // stage NT*512 chunks of 16B; chunk c -> tile=c>>9, row=(c&511)>>2, cc=c&3
    for (int c = tid; c < NT * 512; c += 256) {
      int tile = c >> 9;
      int idx  = c & 511;
      int row  = idx >> 2;
      int cc   = idx & 3;
      const unsigned short* src;
      size_t off;
      if (tile == 0)      { src = Ah; off = (size_t)(row0 + row) * K; }
      else if (tile == 1) { src = Bh; off = (size_t)(col0 + row) * K; }
      else if (tile == 2) { src = Al; off = (size_t)(row0 + row) * K; }
      else                { src = Bl; off = (size_t)(col0 + row) * K; }
      short8 v = *(const short8*)(src + off + kt + cc * 8);
      *(short8*)(&lds[c * 8]) = v;
    }
    __syncthreads();

    short8 aH[4], bH[4], aL[4], bL[4];
    #pragma unroll
    for (int m = 0; m < 4; ++m) {
      int r = wr * 64 + m * 16 + rlane;
      int cidx = wc * 64 + m * 16 + rlane;
      aH[m] = *(const short8*)(&lds[r * 32 + klane]);
      bH[m] = *(const short8*)(&lds[4096 + cidx * 32 + klane]);
      if (SPLIT) {
        aL[m] = *(const short8*)(&lds[2 * 4096 + r * 32 + klane]);
        bL[m] = *(const short8*)(&lds[3 * 4096 + cidx * 32 + klane]);
      }
    }
    #pragma unroll
    for (int mm = 0; mm < 4; ++mm)
      #pragma unroll
      for (int nn = 0; nn < 4; ++nn) {
        acc[mm][nn] = __builtin_amdgcn_mfma_f32_16x16x32_bf16(aH[mm], bH[nn], acc[mm][nn], 0, 0, 0);
        if (SPLIT) {
          acc[mm][nn] = __builtin_amdgcn_mfma_f32_16x16x32_bf16(aH[mm], bL[nn], acc[mm][nn], 0, 0, 0);
          acc[mm][nn] = __builtin_amdgcn_mfma_f32_16x16x32_bf16(aL[mm], bH[nn], acc[mm][nn], 0, 0, 0);
        }
      }
  }

  // C/D layout (verified): col = lane&15, row = (lane>>4)*4 + reg
  const int rl = (lane >> 4) * 4;
  const int cl = lane & 15;
  #pragma unroll
  for (int mm = 0; mm < 4; ++mm)
    #pragma unroll
    for (int nn = 0; nn < 4; ++nn)
      #pragma unroll
      for (int r = 0; r < 4; ++r) {
        int row = row0 + wr * 64 + mm * 16 + rl + r;
        int col = col0 + wc * 64 + nn * 16 + cl;
        Cmat[(size_t)row * N + col] = acc[mm][nn][r];
      }
}

// ---------------- K3a: per-64-t-segment partial sums of k_phi, v ----------
__global__ void cumsum_part(const float* __restrict__ qkv,
                            float* __restrict__ kpart, float* __restrict__ vpart) {
  int idx = blockIdx.x * 256 + threadIdx.x;    // B*NH*32*64 = 65536
  int d   = idx & 63;
  int seg = (idx >> 6) & 31;
  int bh  = idx >> 11;
  int b = bh >> 4, h = bh & 15;
  const float* kb = qkv + (size_t)(b * T_ + seg * 64) * QKV_LD + CD + h * HS_ + d;
  float sk = 0.f, sv = 0.f;
  #pragma unroll 4
  for (int j = 0; j < 64; ++j) {
    float kv = kb[(size_t)j * QKV_LD];
    float vv = kb[(size_t)j * QKV_LD + CD];
    sk += elu1(kv);
    sv += vv;
  }
  kpart[idx] = sk;
  vpart[idx] = sv;
}

// ---------------- K3b: scan partials + walk segment -> k_cum, v_cum -------
__global__ void cumsum_scan(const float* __restrict__ qkv,
                            const float* __restrict__ kpart, const float* __restrict__ vpart,
                            float* __restrict__ kcum, float* __restrict__ vcum) {
  int idx = blockIdx.x * 256 + threadIdx.x;
  int d   = idx & 63;
  int seg = (idx >> 6) & 31;
  int bh  = idx >> 11;
  int b = bh >> 4, h = bh & 15;
  float ok = 0.f, ov = 0.f;
  for (int j = 0; j < seg; ++j) {
    ok += kpart[(bh * 32 + j) * 64 + d];
    ov += vpart[(bh * 32 + j) * 64 + d];
  }
  const float* kb = qkv + (size_t)(b * T_ + seg * 64) * QKV_LD + CD + h * HS_ + d;
  float* kout = kcum + ((size_t)bh * T_ + seg * 64) * HS_ + d;
  float* vout = vcum + ((size_t)bh * T_ + seg * 64) * HS_ + d;
  #pragma unroll 4
  for (int j = 0; j < 64; ++j) {
    ok += elu1(kb[(size_t)j * QKV_LD]);
    ov += kb[(size_t)j * QKV_LD + CD];
    kout[(size_t)j * HS_] = ok;
    vout[(size_t)j * HS_] = ov;
  }
}

// ---------------- K4: K/V set aggregates (cumsum interval differences) ----
__global__ void build_sets(const float* __restrict__ kcum, const float* __restrict__ vcum,
                           float* __restrict__ Ks, float* __restrict__ Vs) {
  int idx = blockIdx.x * 256 + threadIdx.x;    // B*NH*511*64
  if (idx >= B_ * NH_ * NSETS * HS_) return;
  int d  = idx & 63;
  int s  = (idx >> 6) % NSETS;
  int bh = idx / (NSETS * HS_);
  int lvl = 3, base = 0;
  while (s >= base + (T_ >> lvl)) { base += T_ >> lvl; ++lvl; }
  int i  = s - base;
  int r  = ((i + 1) << lvl) - 1;
  int li = i << lvl;
  size_t rowr = ((size_t)bh * T_ + r) * HS_ + d;
  float kr = kcum[rowr], vr = vcum[rowr];
  if (li > 0) {
    size_t rowl = ((size_t)bh * T_ + li - 1) * HS_ + d;
    kr -= kcum[rowl];
    vr -= vcum[rowl];
  }
  Ks[idx] = kr;
  Vs[idx] = vr;
}

// ---------------- K5: online-softmax attention core -----------------------
// Block = (b,h, 64-t chunk), 256 threads: 4 lanes per t, 16 dims each.
// Sets iterated level-major (only r<=t valid sets visited). Tail term last.
__global__ __launch_bounds__(256) void attn_kernel(
    const float* __restrict__ qkv, const float* __restrict__ kcum,
    const float* __restrict__ vcum, const float* __restrict__ Ks,
    const float* __restrict__ Vs, unsigned short* __restrict__ attnb)
{
  int blk = blockIdx.x;           // B*NH*(T/64) = 1024
  int tch = blk & 31;
  int bh  = blk >> 5;
  int b = bh >> 4, h = bh & 15;
  int tid = threadIdx.x;
  int dg  = tid & 3;
  int tl  = tid >> 2;
  int t   = tch * 64 + tl;
  int d0  = dg * 16;
  const float scale = 0.125f;

  const float* qrow = qkv + (size_t)(b * T_ + t) * QKV_LD + h * HS_ + d0;
  float q[16];
  #pragma unroll
  for (int j = 0; j < 4; ++j) {
    float4 v = *(const float4*)(qrow + j * 4);
    q[j*4+0] = v.x; q[j*4+1] = v.y; q[j*4+2] = v.z; q[j*4+3] = v.w;
  }

  float acc[16];
  #pragma unroll
  for (int j = 0; j < 16; ++j) acc[j] = 0.f;
  float mrun = -INFINITY, lrun = 0.f;

  const float* KsB = Ks + (size_t)bh * NSETS * HS_ + d0;
  const float* VsB = Vs + (size_t)bh * NSETS * HS_ + d0;

  #pragma unroll 1
  for (int lvl = 3; lvl <= 11; ++lvl) {
    int cmax = ((tch + 1) * 64) >> lvl;     // block-uniform bound
    int cthr = (t + 1) >> lvl;              // per-thread valid count
    int base = 512 - (512 >> (lvl - 3));
    for (int i = 0; i < cmax; ++i) {
      const float* kp = KsB + (size_t)(base + i) * HS_;
      float z = 0.f;
      #pragma unroll
      for (int j = 0; j < 4; ++j) {
        float4 kv = *(const float4*)(kp + j * 4);
        z += q[j*4+0]*kv.x + q[j*4+1]*kv.y + q[j*4+2]*kv.z + q[j*4+3]*kv.w;
      }
      // all lanes active for the shuffles; validity applied after
      z += __shfl_xor(z, 1);
      z += __shfl_xor(z, 2);
      z *= scale;
      if (i < cthr) {
        float wgt;
        if (z > mrun) {
          float f = __expf(mrun - z);       // exp(-inf)=0 handles first hit
          lrun *= f;
          #pragma unroll
          for (int j = 0; j < 16; ++j) acc[j] *= f;
          mrun = z;
          wgt = 1.f;
        } else {
          wgt = __expf(z - mrun);
        }
        lrun += wgt;
        const float* vp = VsB + (size_t)(base + i) * HS_;
        #pragma unroll
        for (int j = 0; j < 4; ++j) {
          float4 vv = *(const float4*)(vp + j * 4);
          acc[j*4+0] += wgt * vv.x; acc[j*4+1] += wgt * vv.y;
          acc[j*4+2] += wgt * vv.z; acc[j*4+3] += wgt * vv.w;
        }
      }
    }
  }

  // tail: interval [t&~7, t], uses q_phi
  {
    float qp[16];
    #pragma unroll
    for (int j = 0; j < 16; ++j) qp[j] = q[j] > 0.f ? q[j] + 1.f : __expf(q[j]);
    int lt = t & ~7;
    const float* kcr = kcum + ((size_t)bh * T_ + t) * HS_ + d0;
    const float* vcr = vcum + ((size_t)bh * T_ + t) * HS_ + d0;
    float ktl[16], vtl[16];
    if (lt > 0) {
      const float* kpv = kcum + ((size_t)bh * T_ + (lt - 1)) * HS_ + d0;
      const float* vpv = vcum + ((size_t)bh * T_ + (lt - 1)) * HS_ + d0;
      #pragma unroll
      for (int j = 0; j < 16; ++j) { ktl[j] = kcr[j] - kpv[j]; vtl[j] = vcr[j] - vpv[j]; }
    } else {
      #pragma unroll
      for (int j = 0; j < 16; ++j) { ktl[j] = kcr[j]; vtl[j] = vcr[j]; }
    }
    float z = 0.f;
    #pragma unroll
    for (int j = 0; j < 16; ++j) z += qp[j] * ktl[j];
    z += __shfl_xor(z, 1);
    z += __shfl_xor(z, 2);
    z *= scale;
    float wgt;
    if (z > mrun) {
      float f = __expf(mrun - z);
      lrun *= f;
      #pragma unroll
      for (int j = 0; j < 16; ++j) acc[j] *= f;
      mrun = z;
      wgt = 1.f;
    } else {
      wgt = __expf(z - mrun);
    }
    lrun += wgt;
    #pragma unroll
    for (int j = 0; j < 16; ++j) acc[j] += wgt * vtl[j];
  }

  float inv = 1.f / lrun;
  unsigned short* orow = attnb + (size_t)(b * T_ + t) * CD + h * HS_ + d0;
  #pragma unroll
  for (int j = 0; j < 16; ++j) orow[j] = f2bf(acc[j] * inv);
}

// --------------------------------------------------------------------------
extern "C" void kernel_launch(void* const* d_in, const int* in_sizes, int n_in,
                              void* d_out, int out_size, void* d_ws, size_t ws_size,
                              hipStream_t stream) {
  const float* x  = (const float*)d_in[0];   // [B,T,C]
  const float* Wa = (const float*)d_in[1];   // [3C,C]
  const float* Wp = (const float*)d_in[2];   // [C,C]
  float* out = (float*)d_out;                // [B,T,C]

  char* ws = (char*)d_ws;
  size_t off = 0;
  auto alloc = [&](size_t bytes) -> char* {
    char* p = ws + off;
    off += (bytes + 255) & ~(size_t)255;
    return p;
  };

  const int M = B_ * T_;                     // 4096
  float* qkv  = (float*)alloc((size_t)M * QKV_LD * 4);            // 50.3 MB
  float* kcum = (float*)alloc((size_t)B_ * NH_ * T_ * HS_ * 4);   // 16.8 MB
  float* vcum = (float*)alloc((size_t)B_ * NH_ * T_ * HS_ * 4);   // 16.8 MB
  float* kpart = (float*)alloc((size_t)B_ * NH_ * 32 * 64 * 4);   // 0.26 MB
  float* vpart = (float*)alloc((size_t)B_ * NH_ * 32 * 64 * 4);   // 0.26 MB
  unsigned short* wph = (unsigned short*)alloc((size_t)CD * CD * 2);  // 2.1 MB

  // regionA: x_hi/x_lo (live through gemm1) then reused for Ks/Vs
  char* regionA = alloc((size_t)16777216);
  unsigned short* xh = (unsigned short*)regionA;
  unsigned short* xl = (unsigned short*)(regionA + (size_t)M * CD * 2);
  float* Ks = (float*)regionA;
  float* Vs = (float*)(regionA + (size_t)B_ * NH_ * NSETS * HS_ * 4);

  // regionB: Wa_hi/Wa_lo (live through gemm1) then reused for attn bf16
  char* regionB = alloc((size_t)12582912);
  unsigned short* wah = (unsigned short*)regionB;
  unsigned short* wal = (unsigned short*)(regionB + (size_t)3 * CD * CD * 2);
  unsigned short* attnb = (unsigned short*)regionB;

  // K1: splits
  split_kernel<<<dim3((M * CD) / 256), dim3(256), 0, stream>>>(x, xh, xl, M * CD);
  split_kernel<<<dim3((3 * CD * CD) / 256), dim3(256), 0, stream>>>(Wa, wah, wal, 3 * CD * CD);
  split_kernel<<<dim3((CD * CD) / 256), dim3(256), 0, stream>>>(Wp, wph, (unsigned short*)nullptr, CD * CD);

  // K2: qkv = x @ Wa^T  (split-bf16, ~f32 precision)
  gemm_bt<1><<<dim3(QKV_LD / 128, M / 128), dim3(256), 0, stream>>>(
      xh, xl, wah, wal, qkv, M, QKV_LD, CD);

  // K3: phi + cumsums
  cumsum_part<<<dim3(65536 / 256), dim3(256), 0, stream>>>(qkv, kpart, vpart);
  cumsum_scan<<<dim3(65536 / 256), dim3(256), 0, stream>>>(qkv, kpart, vpart, kcum, vcum);

  // K4: set aggregates (reuses regionA — xh/xl dead after gemm1)
  build_sets<<<dim3((B_ * NH_ * NSETS * HS_ + 255) / 256), dim3(256), 0, stream>>>(
      kcum, vcum, Ks, Vs);

  // K5: attention core (writes bf16 into regionB — wah/wal dead after gemm1)
  attn_kernel<<<dim3(B_ * NH_ * (T_ / 64)), dim3(256), 0, stream>>>(
      qkv, kcum, vcum, Ks, Vs, attnb);

  // K7: out = attn @ Wp^T (plain bf16 is precision-sufficient: linear error path)
  gemm_bt<0><<<dim3(CD / 128, M / 128), dim3(256), 0, stream>>>(
      attnb, (const unsigned short*)nullptr, wph, (const unsigned short*)nullptr,
      out, M, CD, CD);
}

// Round 2
// 322.950 us; speedup vs baseline: 3.4083x; 3.4083x over previous
//
#include <hip/hip_runtime.h>
#include <hip/hip_bf16.h>
#include <stdint.h>

// Problem constants (B,T,C,NH,LEVEL) = (2,2048,1024,16,3)
#define B_    2
#define T_    2048
#define CD    1024
#define NH_   16
#define HS_   64
#define NSETS 511        // sum_{l=3..11} 2048>>l
#define NSP   512        // padded
#define QKV_LD 3072

typedef __attribute__((ext_vector_type(8))) short  short8;
typedef __attribute__((ext_vector_type(4))) float  f32x4;

__device__ __forceinline__ unsigned short f2bf(float f) {
  unsigned u = __float_as_uint(f);
  unsigned r = 0x7FFFu + ((u >> 16) & 1u);   // round-to-nearest-even
  return (unsigned short)((u + r) >> 16);
}
__device__ __forceinline__ float bf2f(unsigned short h) {
  return __uint_as_float(((unsigned)h) << 16);
}
__device__ __forceinline__ float elu1(float x) {  // elu(x)+1
  return x > 0.f ? x + 1.f : __expf(x);
}

// ---------------- K1: f32 -> bf16 hi (+ optional lo residual) -------------
__global__ void split_kernel(const float* __restrict__ src,
                             unsigned short* __restrict__ hi,
                             unsigned short* __restrict__ lo, int n) {
  int i = blockIdx.x * 256 + threadIdx.x;
  if (i >= n) return;
  float v = src[i];
  unsigned short h = f2bf(v);
  hi[i] = h;
  if (lo) lo[i] = f2bf(v - bf2f(h));
}

// ---------------- K2/K7: C[M,N] = A[M,K] * B[N,K]^T  (bf16 MFMA) ----------
template<int SPLIT>
__global__ __launch_bounds__(256) void gemm_bt(
    const unsigned short* __restrict__ Ah, const unsigned short* __restrict__ Al,
    const unsigned short* __restrict__ Bh, const unsigned short* __restrict__ Bl,
    float* __restrict__ Cmat, int M, int N, int K)
{
  constexpr int NT = SPLIT ? 4 : 2;
  __shared__ short lds[NT * 128 * 32];

  const int row0 = blockIdx.y * 128;
  const int col0 = blockIdx.x * 128;
  const int tid  = threadIdx.x;
  const int lane = tid & 63;
  const int w    = tid >> 6;
  const int wr   = w >> 1, wc = w & 1;

  f32x4 acc[4][4];
  #pragma unroll
  for (int a = 0; a < 4; ++a)
    #pragma unroll
    for (int b = 0; b < 4; ++b)
      acc[a][b] = (f32x4){0.f, 0.f, 0.f, 0.f};

  const int rlane = lane & 15;
  const int klane = (lane >> 4) * 8;

  for (int kt = 0; kt < K; kt += 32) {
    __syncthreads();
    for (int c = tid; c < NT * 512; c += 256) {
      int tile = c >> 9;
      int idx  = c & 511;
      int row  = idx >> 2;
      int cc   = idx & 3;
      const unsigned short* src;
      size_t off;
      if (tile == 0)      { src = Ah; off = (size_t)(row0 + row) * K; }
      else if (tile == 1) { src = Bh; off = (size_t)(col0 + row) * K; }
      else if (tile == 2) { src = Al; off = (size_t)(row0 + row) * K; }
      else                { src = Bl; off = (size_t)(col0 + row) * K; }
      short8 v = *(const short8*)(src + off + kt + cc * 8);
      *(short8*)(&lds[c * 8]) = v;
    }
    __syncthreads();

    short8 aH[4], bH[4], aL[4], bL[4];
    #pragma unroll
    for (int m = 0; m < 4; ++m) {
      int r = wr * 64 + m * 16 + rlane;
      int cidx = wc * 64 + m * 16 + rlane;
      aH[m] = *(const short8*)(&lds[r * 32 + klane]);
      bH[m] = *(const short8*)(&lds[4096 + cidx * 32 + klane]);
      if (SPLIT) {
        aL[m] = *(const short8*)(&lds[2 * 4096 + r * 32 + klane]);
        bL[m] = *(const short8*)(&lds[3 * 4096 + cidx * 32 + klane]);
      }
    }
    #pragma unroll
    for (int mm = 0; mm < 4; ++mm)
      #pragma unroll
      for (int nn = 0; nn < 4; ++nn) {
        acc[mm][nn] = __builtin_amdgcn_mfma_f32_16x16x32_bf16(aH[mm], bH[nn], acc[mm][nn], 0, 0, 0);
        if (SPLIT) {
          acc[mm][nn] = __builtin_amdgcn_mfma_f32_16x16x32_bf16(aH[mm], bL[nn], acc[mm][nn], 0, 0, 0);
          acc[mm][nn] = __builtin_amdgcn_mfma_f32_16x16x32_bf16(aL[mm], bH[nn], acc[mm][nn], 0, 0, 0);
        }
      }
  }

  const int rl = (lane >> 4) * 4;
  const int cl = lane & 15;
  #pragma unroll
  for (int mm = 0; mm < 4; ++mm)
    #pragma unroll
    for (int nn = 0; nn < 4; ++nn)
      #pragma unroll
      for (int r = 0; r < 4; ++r) {
        int row = row0 + wr * 64 + mm * 16 + rl + r;
        int col = col0 + wc * 64 + nn * 16 + cl;
        Cmat[(size_t)row * N + col] = acc[mm][nn][r];
      }
}

// ---------------- K3a: per-64-t-segment partial sums of k_phi, v ----------
__global__ void cumsum_part(const float* __restrict__ qkv,
                            float* __restrict__ kpart, float* __restrict__ vpart) {
  int idx = blockIdx.x * 256 + threadIdx.x;    // B*NH*32*64 = 65536
  int d   = idx & 63;
  int seg = (idx >> 6) & 31;
  int bh  = idx >> 11;
  int b = bh >> 4, h = bh & 15;
  const float* kb = qkv + (size_t)(b * T_ + seg * 64) * QKV_LD + CD + h * HS_ + d;
  float sk = 0.f, sv = 0.f;
  #pragma unroll 4
  for (int j = 0; j < 64; ++j) {
    float kv = kb[(size_t)j * QKV_LD];
    float vv = kb[(size_t)j * QKV_LD + CD];
    sk += elu1(kv);
    sv += vv;
  }
  kpart[idx] = sk;
  vpart[idx] = sv;
}

// ---------------- K3b: scan partials + walk segment -> k_cum, v_cum -------
__global__ void cumsum_scan(const float* __restrict__ qkv,
                            const float* __restrict__ kpart, const float* __restrict__ vpart,
                            float* __restrict__ kcum, float* __restrict__ vcum) {
  int idx = blockIdx.x * 256 + threadIdx.x;
  int d   = idx & 63;
  int seg = (idx >> 6) & 31;
  int bh  = idx >> 11;
  int b = bh >> 4, h = bh & 15;
  float ok = 0.f, ov = 0.f;
  for (int j = 0; j < seg; ++j) {
    ok += kpart[(bh * 32 + j) * 64 + d];
    ov += vpart[(bh * 32 + j) * 64 + d];
  }
  const float* kb = qkv + (size_t)(b * T_ + seg * 64) * QKV_LD + CD + h * HS_ + d;
  float* kout = kcum + ((size_t)bh * T_ + seg * 64) * HS_ + d;
  float* vout = vcum + ((size_t)bh * T_ + seg * 64) * HS_ + d;
  #pragma unroll 4
  for (int j = 0; j < 64; ++j) {
    ok += elu1(kb[(size_t)j * QKV_LD]);
    ov += kb[(size_t)j * QKV_LD + CD];
    kout[(size_t)j * HS_] = ok;
    vout[(size_t)j * HS_] = ov;
  }
}

// ---------------- K4: sorted-by-r set aggregates ---------------------------
// rank(m,lvl) = (lvl-3) + sum_{j=3..11} (m-8)>>j,  m = (i+1)<<lvl, r = m-1.
// Writes Ksh/Ksl bf16 [bh][512][64], Vs f32 [bh][512][64], r_srt[512].
__global__ void build_sets(const float* __restrict__ kcum, const float* __restrict__ vcum,
                           unsigned short* __restrict__ Ksh, unsigned short* __restrict__ Ksl,
                           float* __restrict__ Vs, int* __restrict__ r_srt) {
  int idx = blockIdx.x * 256 + threadIdx.x;    // B*NH*512*64
  if (idx >= B_ * NH_ * NSP * HS_) return;
  int d  = idx & 63;
  int s  = (idx >> 6) & (NSP - 1);
  int bh = idx >> (6 + 9);
  if (s == NSETS) {                            // padding entry
    size_t o = ((size_t)(bh << 9) + s) * HS_ + d;
    Ksh[o] = 0; Ksl[o] = 0; Vs[o] = 0.f;
    if (bh == 0 && d == 0) r_srt[s] = 0x7fffffff;
    return;
  }
  int lvl = 3, base = 0;
  while (s >= base + (T_ >> lvl)) { base += T_ >> lvl; ++lvl; }
  int i  = s - base;
  int m  = (i + 1) << lvl;
  int r  = m - 1;
  int li = i << lvl;
  int rank = lvl - 3;
  #pragma unroll
  for (int j = 3; j <= 11; ++j) rank += (m - 8) >> j;

  size_t rowr = ((size_t)bh * T_ + r) * HS_ + d;
  float kr = kcum[rowr], vr = vcum[rowr];
  if (li > 0) {
    size_t rowl = ((size_t)bh * T_ + li - 1) * HS_ + d;
    kr -= kcum[rowl];
    vr -= vcum[rowl];
  }
  size_t o = ((size_t)(bh << 9) + rank) * HS_ + d;
  unsigned short kh = f2bf(kr);
  Ksh[o] = kh;
  Ksl[o] = f2bf(kr - bf2f(kh));
  Vs[o]  = vr;
  if (bh == 0 && d == 0) r_srt[rank] = r;
}

// ---------------- K4b: Vst[bh][d][512] bf16 = transpose(Vs) ---------------
__global__ __launch_bounds__(256) void vst_transpose(
    const float* __restrict__ Vs, unsigned short* __restrict__ Vst) {
  __shared__ float tile[64][65];
  int bh = blockIdx.x >> 3;
  int s0 = (blockIdx.x & 7) * 64;
  int tid = threadIdx.x;
  int srow = tid >> 2, c0 = (tid & 3) * 16;
  const float* src = Vs + ((size_t)(bh << 9) + s0 + srow) * HS_ + c0;
  #pragma unroll
  for (int j = 0; j < 4; ++j) {
    float4 v = *(const float4*)(src + j * 4);
    tile[srow][c0 + j*4 + 0] = v.x; tile[srow][c0 + j*4 + 1] = v.y;
    tile[srow][c0 + j*4 + 2] = v.z; tile[srow][c0 + j*4 + 3] = v.w;
  }
  __syncthreads();
  int d = tid >> 2, sq = (tid & 3) * 16;
  short8 a, b;
  #pragma unroll
  for (int j = 0; j < 8; ++j) {
    a[j] = (short)f2bf(tile[sq + j][d]);
    b[j] = (short)f2bf(tile[sq + 8 + j][d]);
  }
  unsigned short* dst = Vst + ((size_t)(bh << 6) + d) * NSP + s0 + sq;
  *(short8*)dst = a;
  *(short8*)(dst + 8) = b;
}

// ---------------- K5: MFMA flash attention over sorted sets ---------------
// Block = (bh, 64 t-rows), 4 waves x 16 rows. 16x16x32 bf16 MFMA.
// QK^T split-bf16 (3 MFMAs), online softmax, P via swizzled LDS, PV MFMA.
__global__ __launch_bounds__(256) void attn_mfma(
    const float* __restrict__ qkv, const float* __restrict__ kcum,
    const float* __restrict__ vcum,
    const unsigned short* __restrict__ Ksh, const unsigned short* __restrict__ Ksl,
    const unsigned short* __restrict__ Vst, const int* __restrict__ r_srt,
    unsigned short* __restrict__ attnb)
{
  __shared__ short Qh[64 * 64];
  __shared__ short Ql[64 * 64];
  __shared__ short Pl[4 * 16 * 64];

  const int blk = blockIdx.x;           // 32 bh * 32 chunks
  const int tch = blk & 31;
  const int bh  = blk >> 5;
  const int b = bh >> 4, h = bh & 15;
  const int t0 = tch * 64;
  const int tid = threadIdx.x;
  const int lane = tid & 63;
  const int w = tid >> 6;
  const int col = lane & 15;
  const float scale = 0.125f;

  // ---- Phase 1: load Q tile f32, split to bf16 hi/lo, swizzled LDS ----
  {
    int row = tid >> 2;
    int d0  = (tid & 3) * 16;
    const float* qr = qkv + (size_t)(b * T_ + t0 + row) * QKV_LD + h * HS_ + d0;
    float qv[16];
    #pragma unroll
    for (int j = 0; j < 4; ++j) {
      float4 v = *(const float4*)(qr + j * 4);
      qv[j*4+0] = v.x; qv[j*4+1] = v.y; qv[j*4+2] = v.z; qv[j*4+3] = v.w;
    }
    short8 hh[2], ll[2];
    #pragma unroll
    for (int c = 0; c < 2; ++c)
      #pragma unroll
      for (int j = 0; j < 8; ++j) {
        float f = qv[c*8+j];
        unsigned short hi = f2bf(f);
        hh[c][j] = (short)hi;
        ll[c][j] = (short)f2bf(f - bf2f(hi));
      }
    int swz = (row & 7) << 4;
    #pragma unroll
    for (int c = 0; c < 2; ++c) {
      int addr = (row * 128 + d0 * 2 + c * 16) ^ swz;
      *(short8*)((char*)Qh + addr) = hh[c];
      *(short8*)((char*)Ql + addr) = ll[c];
    }
  }
  __syncthreads();

  // ---- per-lane state (C-layout: rows (lane>>4)*4+r, col lane&15) ----
  int rows[4];
  #pragma unroll
  for (int r = 0; r < 4; ++r) rows[r] = t0 + w * 16 + (lane >> 4) * 4 + r;

  f32x4 O[4];
  #pragma unroll
  for (int f = 0; f < 4; ++f) O[f] = (f32x4){0.f, 0.f, 0.f, 0.f};
  float mrun[4] = {-INFINITY, -INFINITY, -INFINITY, -INFINITY};
  float lrun[4] = {0.f, 0.f, 0.f, 0.f};

  int nmax = 0;
  #pragma unroll
  for (int j = 3; j <= 11; ++j) nmax += (t0 + 64) >> j;
  const int ntiles = (nmax + 63) >> 6;

  const int arow  = w * 16 + col;
  const int aswz  = (arow & 7) << 4;
  const int kgrp  = (lane >> 4) * 8;

  for (int tile = 0; tile < ntiles; ++tile) {
    const int s0 = tile * 64;
    f32x4 S[4];
    #pragma unroll
    for (int f = 0; f < 4; ++f) S[f] = (f32x4){0.f, 0.f, 0.f, 0.f};

    #pragma unroll
    for (int ks = 0; ks < 2; ++ks) {
      int abyte = (arow * 128 + (kgrp + ks * 32) * 2) ^ aswz;
      short8 aH = *(const short8*)((const char*)Qh + abyte);
      short8 aL = *(const short8*)((const char*)Ql + abyte);
      #pragma unroll
      for (int f = 0; f < 4; ++f) {
        size_t ko = ((size_t)(bh << 9) + s0 + f * 16 + col) * HS_ + kgrp + ks * 32;
        short8 bHv = *(const short8*)(Ksh + ko);
        short8 bLv = *(const short8*)(Ksl + ko);
        S[f] = __builtin_amdgcn_mfma_f32_16x16x32_bf16(aH, bHv, S[f], 0, 0, 0);
        S[f] = __builtin_amdgcn_mfma_f32_16x16x32_bf16(aH, bLv, S[f], 0, 0, 0);
        S[f] = __builtin_amdgcn_mfma_f32_16x16x32_bf16(aL, bHv, S[f], 0, 0, 0);
      }
    }

    // ---- mask + online softmax ----
    int rsv[4];
    #pragma unroll
    for (int f = 0; f < 4; ++f) rsv[f] = r_srt[s0 + f * 16 + col];

    float zv[4][4];
    #pragma unroll
    for (int f = 0; f < 4; ++f)
      #pragma unroll
      for (int r = 0; r < 4; ++r)
        zv[f][r] = (rsv[f] > rows[r]) ? -INFINITY : S[f][r] * scale;

    #pragma unroll
    for (int r = 0; r < 4; ++r) {
      float mt = fmaxf(fmaxf(zv[0][r], zv[1][r]), fmaxf(zv[2][r], zv[3][r]));
      mt = fmaxf(mt, __shfl_xor(mt, 1));
      mt = fmaxf(mt, __shfl_xor(mt, 2));
      mt = fmaxf(mt, __shfl_xor(mt, 4));
      mt = fmaxf(mt, __shfl_xor(mt, 8));
      float mv = fmaxf(mrun[r], mt);
      float mm = (mv == -INFINITY) ? 0.f : mv;
      float fs = (mrun[r] == -INFINITY) ? 0.f : __expf(mrun[r] - mm);
      float ps = 0.f;
      #pragma unroll
      for (int f = 0; f < 4; ++f) {
        float p = __expf(zv[f][r] - mm);
        zv[f][r] = p;                       // reuse as P
        ps += p;
      }
      ps += __shfl_xor(ps, 1);
      ps += __shfl_xor(ps, 2);
      ps += __shfl_xor(ps, 4);
      ps += __shfl_xor(ps, 8);
      lrun[r] = lrun[r] * fs + ps;
      #pragma unroll
      for (int f = 0; f < 4; ++f) O[f][r] *= fs;
      mrun[r] = mv;
    }

    // ---- P -> bf16 -> wave-private swizzled LDS ----
    char* pw = (char*)Pl + w * 2048;
    #pragma unroll
    for (int r = 0; r < 4; ++r) {
      int rowr = (lane >> 4) * 4 + r;
      int rswz = (rowr & 7) << 4;
      #pragma unroll
      for (int f = 0; f < 4; ++f) {
        int addr = (rowr * 128 + (f * 16 + col) * 2) ^ rswz;
        *(unsigned short*)(pw + addr) = f2bf(zv[f][r]);
      }
    }

    // ---- PV MFMA: O += P[16x64] * Vst^T ----
    #pragma unroll
    for (int ks = 0; ks < 2; ++ks) {
      int pbyte = (col * 128 + (kgrp + ks * 32) * 2) ^ ((col & 7) << 4);
      short8 pa = *(const short8*)(pw + pbyte);
      #pragma unroll
      for (int f = 0; f < 4; ++f) {
        const unsigned short* vb = Vst + ((size_t)(bh << 6) + f * 16 + col) * NSP
                                   + s0 + kgrp + ks * 32;
        short8 bv = *(const short8*)vb;
        O[f] = __builtin_amdgcn_mfma_f32_16x16x32_bf16(pa, bv, O[f], 0, 0, 0);
      }
    }
  }

  // ---- tail term: interval [t&~7, t] with q_phi, per-row VALU ----
  float ztail;
  {
    int trow = lane >> 2;
    int t = t0 + w * 16 + trow;
    int d0 = (lane & 3) * 16;
    const float* qr = qkv + (size_t)(b * T_ + t) * QKV_LD + h * HS_ + d0;
    float qv[16];
    #pragma unroll
    for (int j = 0; j < 4; ++j) {
      float4 v = *(const float4*)(qr + j * 4);
      qv[j*4+0] = v.x; qv[j*4+1] = v.y; qv[j*4+2] = v.z; qv[j*4+3] = v.w;
    }
    int lt = t & ~7;
    const float* kc1 = kcum + ((size_t)bh * T_ + t) * HS_ + d0;
    float kt[16];
    if (lt > 0) {
      const float* kc0 = kcum + ((size_t)bh * T_ + (lt - 1)) * HS_ + d0;
      #pragma unroll
      for (int j = 0; j < 16; ++j) kt[j] = kc1[j] - kc0[j];
    } else {
      #pragma unroll
      for (int j = 0; j < 16; ++j) kt[j] = kc1[j];
    }
    float z = 0.f;
    #pragma unroll
    for (int j = 0; j < 16; ++j) {
      float qp = qv[j] > 0.f ? qv[j] + 1.f : __expf(qv[j]);
      z += qp * kt[j];
    }
    z += __shfl_xor(z, 1);
    z += __shfl_xor(z, 2);
    ztail = z * scale;
  }

  #pragma unroll
  for (int r = 0; r < 4; ++r) {
    float zt = __shfl(ztail, ((lane >> 4) * 4 + r) * 4);
    float mv = fmaxf(mrun[r], zt);
    float fs = (mrun[r] == -INFINITY) ? 0.f : __expf(mrun[r] - mv);
    float pwgt = __expf(zt - mv);
    lrun[r] = lrun[r] * fs + pwgt;
    int tr = rows[r];
    int ltr = tr & ~7;
    #pragma unroll
    for (int f = 0; f < 4; ++f) {
      int d = f * 16 + col;
      float v1 = vcum[((size_t)bh * T_ + tr) * HS_ + d];
      float vt = (ltr > 0) ? v1 - vcum[((size_t)bh * T_ + (ltr - 1)) * HS_ + d] : v1;
      O[f][r] = O[f][r] * fs + pwgt * vt;
    }
  }

  // ---- epilogue: normalize, write bf16 ----
  #pragma unroll
  for (int r = 0; r < 4; ++r) {
    float inv = 1.f / lrun[r];
    unsigned short* orow = attnb + (size_t)(b * T_ + rows[r]) * CD + h * HS_;
    #pragma unroll
    for (int f = 0; f < 4; ++f)
      orow[f * 16 + col] = f2bf(O[f][r] * inv);
  }
}

// --------------------------------------------------------------------------
extern "C" void kernel_launch(void* const* d_in, const int* in_sizes, int n_in,
                              void* d_out, int out_size, void* d_ws, size_t ws_size,
                              hipStream_t stream) {
  const float* x  = (const float*)d_in[0];   // [B,T,C]
  const float* Wa = (const float*)d_in[1];   // [3C,C]
  const float* Wp = (const float*)d_in[2];   // [C,C]
  float* out = (float*)d_out;                // [B,T,C]

  char* ws = (char*)d_ws;
  size_t off = 0;
  auto alloc = [&](size_t bytes) -> char* {
    char* p = ws + off;
    off += (bytes + 255) & ~(size_t)255;
    return p;
  };

  const int M = B_ * T_;                     // 4096
  float* qkv  = (float*)alloc((size_t)M * QKV_LD * 4);            // 50.3 MB
  float* kcum = (float*)alloc((size_t)B_ * NH_ * T_ * HS_ * 4);   // 16.8 MB
  float* vcum = (float*)alloc((size_t)B_ * NH_ * T_ * HS_ * 4);   // 16.8 MB
  float* kpart = (float*)alloc((size_t)B_ * NH_ * 32 * 64 * 4);
  float* vpart = (float*)alloc((size_t)B_ * NH_ * 32 * 64 * 4);
  unsigned short* wph = (unsigned short*)alloc((size_t)CD * CD * 2);

  // regionA: x_hi/x_lo (live through gemm1), then sorted set arrays
  char* regionA = alloc((size_t)16777216);
  unsigned short* xh = (unsigned short*)regionA;
  unsigned short* xl = (unsigned short*)(regionA + (size_t)M * CD * 2);
  const size_t SETS_ELEMS = (size_t)B_ * NH_ * NSP * HS_;          // 2M
  unsigned short* Ksh = (unsigned short*)regionA;                  // 4 MB
  unsigned short* Ksl = Ksh + SETS_ELEMS;                          // 4 MB
  float*          Vss = (float*)(regionA + 2 * SETS_ELEMS * 2);    // 8 MB
  unsigned short* Vst = (unsigned short*)(regionA + 2 * SETS_ELEMS * 2 + SETS_ELEMS * 4);
  int*            r_srt = (int*)(regionA + 2 * SETS_ELEMS * 2 + SETS_ELEMS * 4 + SETS_ELEMS * 2);

  // regionB: Wa_hi/Wa_lo (live through gemm1), then attn bf16 output
  char* regionB = alloc((size_t)12582912);
  unsigned short* wah = (unsigned short*)regionB;
  unsigned short* wal = (unsigned short*)(regionB + (size_t)3 * CD * CD * 2);
  unsigned short* attnb = (unsigned short*)regionB;

  // K1: splits
  split_kernel<<<dim3((M * CD) / 256), dim3(256), 0, stream>>>(x, xh, xl, M * CD);
  split_kernel<<<dim3((3 * CD * CD) / 256), dim3(256), 0, stream>>>(Wa, wah, wal, 3 * CD * CD);
  split_kernel<<<dim3((CD * CD) / 256), dim3(256), 0, stream>>>(Wp, wph, (unsigned short*)nullptr, CD * CD);

  // K2: qkv = x @ Wa^T  (split-bf16, ~f32 precision)
  gemm_bt<1><<<dim3(QKV_LD / 128, M / 128), dim3(256), 0, stream>>>(
      xh, xl, wah, wal, qkv, M, QKV_LD, CD);

  // K3: phi + cumsums
  cumsum_part<<<dim3(65536 / 256), dim3(256), 0, stream>>>(qkv, kpart, vpart);
  cumsum_scan<<<dim3(65536 / 256), dim3(256), 0, stream>>>(qkv, kpart, vpart, kcum, vcum);

  // K4: sorted set aggregates (reuses regionA — xh/xl dead after gemm1)
  build_sets<<<dim3((B_ * NH_ * NSP * HS_) / 256), dim3(256), 0, stream>>>(
      kcum, vcum, Ksh, Ksl, Vss, r_srt);
  vst_transpose<<<dim3(B_ * NH_ * (NSP / 64)), dim3(256), 0, stream>>>(Vss, Vst);

  // K5: MFMA attention (writes bf16 into regionB — wah/wal dead after gemm1)
  attn_mfma<<<dim3(B_ * NH_ * (T_ / 64)), dim3(256), 0, stream>>>(
      qkv, kcum, vcum, Ksh, Ksl, Vst, r_srt, attnb);

  // K7: out = attn @ Wp^T
  gemm_bt<0><<<dim3(CD / 128, M / 128), dim3(256), 0, stream>>>(
      attnb, (const unsigned short*)nullptr, wph, (const unsigned short*)nullptr,
      out, M, CD, CD);
}

// Round 3
// 282.930 us; speedup vs baseline: 3.8904x; 1.1414x over previous
//
#include <hip/hip_runtime.h>
#include <hip/hip_bf16.h>
#include <stdint.h>

// Problem constants (B,T,C,NH,LEVEL) = (2,2048,1024,16,3)
#define B_    2
#define T_    2048
#define CD    1024
#define NH_   16
#define HS_   64
#define NSETS 511        // sum_{l=3..11} 2048>>l
#define NSP   512        // padded
#define QKV_LD 3072

typedef __attribute__((ext_vector_type(8))) short  short8;
typedef __attribute__((ext_vector_type(4))) float  f32x4;

__device__ __forceinline__ unsigned short f2bf(float f) {
  unsigned u = __float_as_uint(f);
  unsigned r = 0x7FFFu + ((u >> 16) & 1u);   // round-to-nearest-even
  return (unsigned short)((u + r) >> 16);
}
__device__ __forceinline__ float bf2f(unsigned short h) {
  return __uint_as_float(((unsigned)h) << 16);
}
__device__ __forceinline__ float elu1(float x) {  // elu(x)+1
  return x > 0.f ? x + 1.f : __expf(x);
}
__device__ __forceinline__ void gload16(const unsigned short* g, short* l) {
  __builtin_amdgcn_global_load_lds(
      (const __attribute__((address_space(1))) unsigned int*)g,
      (__attribute__((address_space(3))) unsigned int*)l, 16, 0, 0);
}

// ---------------- K1: f32 -> bf16 hi (+ optional lo residual) -------------
__global__ void split_kernel(const float* __restrict__ src,
                             unsigned short* __restrict__ hi,
                             unsigned short* __restrict__ lo, int n) {
  int i = blockIdx.x * 256 + threadIdx.x;
  if (i >= n) return;
  float v = src[i];
  unsigned short h = f2bf(v);
  hi[i] = h;
  if (lo) lo[i] = f2bf(v - bf2f(h));
}

// ---------------- K2/K7: C[M,N] = A[M,K] * B[N,K]^T  (bf16 MFMA) ----------
// m97 structure: global_load_lds width=16 staging, 2-barrier K-loop.
// LDS layout: [tile][row][32 shorts], 64B rows, chunk-XOR swizzle c^(row&3)
// applied on BOTH the global source (pre-swizzle) and the ds_read address.
template<int SPLIT>
__global__ __launch_bounds__(256) void gemm_bt(
    const unsigned short* __restrict__ Ah, const unsigned short* __restrict__ Al,
    const unsigned short* __restrict__ Bh, const unsigned short* __restrict__ Bl,
    float* __restrict__ Cmat, int M, int N, int K)
{
  constexpr int NT = SPLIT ? 4 : 2;
  __shared__ short lds[NT * 4096];                   // 8KB per tile

  // XCD-aware bijective swizzle (grid %8 == 0 for both instantiations)
  const int nwg = gridDim.x;
  const int cpx = nwg >> 3;
  const int bid = blockIdx.x;
  const int swb = (bid & 7) * cpx + (bid >> 3);
  const int nbx = N >> 7;
  const int bx = swb % nbx;
  const int by = swb / nbx;

  const int row0 = by * 128;
  const int col0 = bx * 128;
  const int tid  = threadIdx.x;
  const int lane = tid & 63;
  const int w    = tid >> 6;
  const int wr   = w >> 1, wc = w & 1;

  f32x4 acc[4][4];
  #pragma unroll
  for (int a = 0; a < 4; ++a)
    #pragma unroll
    for (int b = 0; b < 4; ++b)
      acc[a][b] = (f32x4){0.f, 0.f, 0.f, 0.f};

  const int rlane = lane & 15;
  const int kgrp  = lane >> 4;                       // 0..3 (16B chunk)
  const int rsw   = (kgrp ^ (rlane & 3)) << 4;       // read-side swizzled chunk byte

  // staging: each wave owns tile(s); lane l -> row l>>2, chunk l&3 (linear LDS)
  const int slr = lane >> 2;                         // row within 16-row block
  const int sch = (lane & 3) ^ (slr & 3);            // pre-swizzled source chunk

  const unsigned short* ssrc;
  size_t srb;
  short* sbase;
  if (SPLIT) {
    ssrc = (w == 0) ? Ah : (w == 1) ? Bh : (w == 2) ? Al : Bl;
    srb  = (w & 1) ? (size_t)col0 : (size_t)row0;
    sbase = &lds[w * 4096];
  } else {
    ssrc = (w & 1) ? Bh : Ah;
    srb  = (w & 1) ? (size_t)col0 : (size_t)row0;
    sbase = &lds[(w & 1) * 4096 + (w >> 1) * 2048];  // half-tile per wave
    srb += (size_t)(w >> 1) * 64;
  }

  for (int kt = 0; kt < K; kt += 32) {
    __syncthreads();
    const unsigned short* g0 = ssrc + (srb + slr) * K + kt + (sch << 3);
    if (SPLIT) {
      #pragma unroll
      for (int i = 0; i < 8; ++i)
        gload16(g0 + (size_t)i * 16 * K, sbase + i * 512);
    } else {
      #pragma unroll
      for (int i = 0; i < 4; ++i)
        gload16(g0 + (size_t)i * 16 * K, sbase + i * 512);
    }
    __syncthreads();   // compiler drains vmcnt(0) here

    short8 aH[4], bH[4], aL[4], bL[4];
    #pragma unroll
    for (int m = 0; m < 4; ++m) {
      int r    = wr * 64 + m * 16 + rlane;
      int cidx = wc * 64 + m * 16 + rlane;
      aH[m] = *(const short8*)((const char*)lds + r * 64 + rsw);
      bH[m] = *(const short8*)((const char*)lds + 8192 + cidx * 64 + rsw);
      if (SPLIT) {
        aL[m] = *(const short8*)((const char*)lds + 16384 + r * 64 + rsw);
        bL[m] = *(const short8*)((const char*)lds + 24576 + cidx * 64 + rsw);
      }
    }
    #pragma unroll
    for (int mm = 0; mm < 4; ++mm)
      #pragma unroll
      for (int nn = 0; nn < 4; ++nn) {
        acc[mm][nn] = __builtin_amdgcn_mfma_f32_16x16x32_bf16(aH[mm], bH[nn], acc[mm][nn], 0, 0, 0);
        if (SPLIT) {
          acc[mm][nn] = __builtin_amdgcn_mfma_f32_16x16x32_bf16(aH[mm], bL[nn], acc[mm][nn], 0, 0, 0);
          acc[mm][nn] = __builtin_amdgcn_mfma_f32_16x16x32_bf16(aL[mm], bH[nn], acc[mm][nn], 0, 0, 0);
        }
      }
  }

  const int rl = (lane >> 4) * 4;
  const int cl = lane & 15;
  #pragma unroll
  for (int mm = 0; mm < 4; ++mm)
    #pragma unroll
    for (int nn = 0; nn < 4; ++nn)
      #pragma unroll
      for (int r = 0; r < 4; ++r) {
        int row = row0 + wr * 64 + mm * 16 + rl + r;
        int col = col0 + wc * 64 + nn * 16 + cl;
        Cmat[(size_t)row * N + col] = acc[mm][nn][r];
      }
}

// ---------------- K3a: per-seg partial sums (coalesced float4 columns) ----
// block = (b, seg, half): half 0 = k (phi applied), 1 = v. 256 thr x 4 cols.
__global__ __launch_bounds__(256) void cs_part(const float* __restrict__ qkv,
                                               float* __restrict__ part) {
  int blk = blockIdx.x;                 // B*32*2
  int q   = blk & 1;
  int seg = (blk >> 1) & 31;
  int b   = blk >> 6;
  int c   = threadIdx.x * 4;            // 0..1023
  const float* src = qkv + (size_t)(b * T_ + seg * 64) * QKV_LD + CD + q * CD + c;
  float4 s = {0.f, 0.f, 0.f, 0.f};
  #pragma unroll 4
  for (int j = 0; j < 64; ++j) {
    float4 v = *(const float4*)(src + (size_t)j * QKV_LD);
    if (q == 0) {
      s.x += elu1(v.x); s.y += elu1(v.y); s.z += elu1(v.z); s.w += elu1(v.w);
    } else {
      s.x += v.x; s.y += v.y; s.z += v.z; s.w += v.w;
    }
  }
  *(float4*)(part + ((size_t)(b * 32 + seg) * 2048) + q * 1024 + c) = s;
}

// ---------------- K3b: exclusive prefix over 32 segs per column ----------
__global__ void cs_prefix(float* __restrict__ part) {
  int idx = blockIdx.x * 256 + threadIdx.x;      // B*2048
  int b  = idx >> 11;
  int cc = idx & 2047;
  float run = 0.f;
  #pragma unroll 8
  for (int s = 0; s < 32; ++s) {
    size_t o = (size_t)(b * 32 + s) * 2048 + cc;
    float t = part[o];
    part[o] = run;
    run += t;
  }
}

// ---------------- K3c: final walk -> kcum / vcum --------------------------
__global__ __launch_bounds__(256) void cs_final(const float* __restrict__ qkv,
                                                const float* __restrict__ part,
                                                float* __restrict__ kcum,
                                                float* __restrict__ vcum) {
  int blk = blockIdx.x;
  int q   = blk & 1;
  int seg = (blk >> 1) & 31;
  int b   = blk >> 6;
  int c   = threadIdx.x * 4;
  int h   = c >> 6, d = c & 63;
  const float* src = qkv + (size_t)(b * T_ + seg * 64) * QKV_LD + CD + q * CD + c;
  float* dst = (q == 0 ? kcum : vcum) + ((size_t)(b * NH_ + h) * T_ + seg * 64) * HS_ + d;
  float4 s = *(const float4*)(part + ((size_t)(b * 32 + seg) * 2048) + q * 1024 + c);
  #pragma unroll 4
  for (int j = 0; j < 64; ++j) {
    float4 v = *(const float4*)(src + (size_t)j * QKV_LD);
    if (q == 0) {
      s.x += elu1(v.x); s.y += elu1(v.y); s.z += elu1(v.z); s.w += elu1(v.w);
    } else {
      s.x += v.x; s.y += v.y; s.z += v.z; s.w += v.w;
    }
    *(float4*)(dst + (size_t)j * HS_) = s;
  }
}

// ---------------- K4: sorted-by-r set aggregates ---------------------------
// rank(m,lvl) = (lvl-3) + sum_{j=3..11} (m-8)>>j,  m = (i+1)<<lvl, r = m-1.
__global__ void build_sets(const float* __restrict__ kcum, const float* __restrict__ vcum,
                           unsigned short* __restrict__ Ksh, unsigned short* __restrict__ Ksl,
                           float* __restrict__ Vs, int* __restrict__ r_srt) {
  int idx = blockIdx.x * 256 + threadIdx.x;    // B*NH*512*64
  if (idx >= B_ * NH_ * NSP * HS_) return;
  int d  = idx & 63;
  int s  = (idx >> 6) & (NSP - 1);
  int bh = idx >> (6 + 9);
  if (s == NSETS) {                            // padding entry
    size_t o = ((size_t)(bh << 9) + s) * HS_ + d;
    Ksh[o] = 0; Ksl[o] = 0; Vs[o] = 0.f;
    if (bh == 0 && d == 0) r_srt[s] = 0x7fffffff;
    return;
  }
  int lvl = 3, base = 0;
  while (s >= base + (T_ >> lvl)) { base += T_ >> lvl; ++lvl; }
  int i  = s - base;
  int m  = (i + 1) << lvl;
  int r  = m - 1;
  int li = i << lvl;
  int rank = lvl - 3;
  #pragma unroll
  for (int j = 3; j <= 11; ++j) rank += (m - 8) >> j;

  size_t rowr = ((size_t)bh * T_ + r) * HS_ + d;
  float kr = kcum[rowr], vr = vcum[rowr];
  if (li > 0) {
    size_t rowl = ((size_t)bh * T_ + li - 1) * HS_ + d;
    kr -= kcum[rowl];
    vr -= vcum[rowl];
  }
  size_t o = ((size_t)(bh << 9) + rank) * HS_ + d;
  unsigned short kh = f2bf(kr);
  Ksh[o] = kh;
  Ksl[o] = f2bf(kr - bf2f(kh));
  Vs[o]  = vr;
  if (bh == 0 && d == 0) r_srt[rank] = r;
}

// ---------------- K4b: Vst[bh][d][512] bf16 = transpose(Vs) ---------------
__global__ __launch_bounds__(256) void vst_transpose(
    const float* __restrict__ Vs, unsigned short* __restrict__ Vst) {
  __shared__ float tile[64][65];
  int bh = blockIdx.x >> 3;
  int s0 = (blockIdx.x & 7) * 64;
  int tid = threadIdx.x;
  int srow = tid >> 2, c0 = (tid & 3) * 16;
  const float* src = Vs + ((size_t)(bh << 9) + s0 + srow) * HS_ + c0;
  #pragma unroll
  for (int j = 0; j < 4; ++j) {
    float4 v = *(const float4*)(src + j * 4);
    tile[srow][c0 + j*4 + 0] = v.x; tile[srow][c0 + j*4 + 1] = v.y;
    tile[srow][c0 + j*4 + 2] = v.z; tile[srow][c0 + j*4 + 3] = v.w;
  }
  __syncthreads();
  int d = tid >> 2, sq = (tid & 3) * 16;
  short8 a, b;
  #pragma unroll
  for (int j = 0; j < 8; ++j) {
    a[j] = (short)f2bf(tile[sq + j][d]);
    b[j] = (short)f2bf(tile[sq + 8 + j][d]);
  }
  unsigned short* dst = Vst + ((size_t)(bh << 6) + d) * NSP + s0 + sq;
  *(short8*)dst = a;
  *(short8*)(dst + 8) = b;
}

// ---------------- K5: MFMA flash attention over sorted sets ---------------
__global__ __launch_bounds__(256) void attn_mfma(
    const float* __restrict__ qkv, const float* __restrict__ kcum,
    const float* __restrict__ vcum,
    const unsigned short* __restrict__ Ksh, const unsigned short* __restrict__ Ksl,
    const unsigned short* __restrict__ Vst, const int* __restrict__ r_srt,
    unsigned short* __restrict__ attnb)
{
  __shared__ short Qh[64 * 64];
  __shared__ short Ql[64 * 64];
  __shared__ short Pl[4 * 16 * 64];

  const int blk = blockIdx.x;           // 32 bh * 32 chunks
  const int tch = blk & 31;
  const int bh  = blk >> 5;
  const int b = bh >> 4, h = bh & 15;
  const int t0 = tch * 64;
  const int tid = threadIdx.x;
  const int lane = tid & 63;
  const int w = tid >> 6;
  const int col = lane & 15;
  const float scale = 0.125f;

  // ---- Phase 1: load Q tile f32, split to bf16 hi/lo, swizzled LDS ----
  {
    int row = tid >> 2;
    int d0  = (tid & 3) * 16;
    const float* qr = qkv + (size_t)(b * T_ + t0 + row) * QKV_LD + h * HS_ + d0;
    float qv[16];
    #pragma unroll
    for (int j = 0; j < 4; ++j) {
      float4 v = *(const float4*)(qr + j * 4);
      qv[j*4+0] = v.x; qv[j*4+1] = v.y; qv[j*4+2] = v.z; qv[j*4+3] = v.w;
    }
    short8 hh[2], ll[2];
    #pragma unroll
    for (int c = 0; c < 2; ++c)
      #pragma unroll
      for (int j = 0; j < 8; ++j) {
        float f = qv[c*8+j];
        unsigned short hi = f2bf(f);
        hh[c][j] = (short)hi;
        ll[c][j] = (short)f2bf(f - bf2f(hi));
      }
    int swz = (row & 7) << 4;
    #pragma unroll
    for (int c = 0; c < 2; ++c) {
      int addr = (row * 128 + d0 * 2 + c * 16) ^ swz;
      *(short8*)((char*)Qh + addr) = hh[c];
      *(short8*)((char*)Ql + addr) = ll[c];
    }
  }
  __syncthreads();

  int rows[4];
  #pragma unroll
  for (int r = 0; r < 4; ++r) rows[r] = t0 + w * 16 + (lane >> 4) * 4 + r;

  f32x4 O[4];
  #pragma unroll
  for (int f = 0; f < 4; ++f) O[f] = (f32x4){0.f, 0.f, 0.f, 0.f};
  float mrun[4] = {-INFINITY, -INFINITY, -INFINITY, -INFINITY};
  float lrun[4] = {0.f, 0.f, 0.f, 0.f};

  int nmax = 0;
  #pragma unroll
  for (int j = 3; j <= 11; ++j) nmax += (t0 + 64) >> j;
  const int ntiles = (nmax + 63) >> 6;

  const int arow  = w * 16 + col;
  const int aswz  = (arow & 7) << 4;
  const int kgrp  = (lane >> 4) * 8;

  for (int tile = 0; tile < ntiles; ++tile) {
    const int s0 = tile * 64;
    f32x4 S[4];
    #pragma unroll
    for (int f = 0; f < 4; ++f) S[f] = (f32x4){0.f, 0.f, 0.f, 0.f};

    #pragma unroll
    for (int ks = 0; ks < 2; ++ks) {
      int abyte = (arow * 128 + (kgrp + ks * 32) * 2) ^ aswz;
      short8 aH = *(const short8*)((const char*)Qh + abyte);
      short8 aL = *(const short8*)((const char*)Ql + abyte);
      #pragma unroll
      for (int f = 0; f < 4; ++f) {
        size_t ko = ((size_t)(bh << 9) + s0 + f * 16 + col) * HS_ + kgrp + ks * 32;
        short8 bHv = *(const short8*)(Ksh + ko);
        short8 bLv = *(const short8*)(Ksl + ko);
        S[f] = __builtin_amdgcn_mfma_f32_16x16x32_bf16(aH, bHv, S[f], 0, 0, 0);
        S[f] = __builtin_amdgcn_mfma_f32_16x16x32_bf16(aH, bLv, S[f], 0, 0, 0);
        S[f] = __builtin_amdgcn_mfma_f32_16x16x32_bf16(aL, bHv, S[f], 0, 0, 0);
      }
    }

    int rsv[4];
    #pragma unroll
    for (int f = 0; f < 4; ++f) rsv[f] = r_srt[s0 + f * 16 + col];

    float zv[4][4];
    #pragma unroll
    for (int f = 0; f < 4; ++f)
      #pragma unroll
      for (int r = 0; r < 4; ++r)
        zv[f][r] = (rsv[f] > rows[r]) ? -INFINITY : S[f][r] * scale;

    #pragma unroll
    for (int r = 0; r < 4; ++r) {
      float mt = fmaxf(fmaxf(zv[0][r], zv[1][r]), fmaxf(zv[2][r], zv[3][r]));
      mt = fmaxf(mt, __shfl_xor(mt, 1));
      mt = fmaxf(mt, __shfl_xor(mt, 2));
      mt = fmaxf(mt, __shfl_xor(mt, 4));
      mt = fmaxf(mt, __shfl_xor(mt, 8));
      float mv = fmaxf(mrun[r], mt);
      float mm = (mv == -INFINITY) ? 0.f : mv;
      float fs = (mrun[r] == -INFINITY) ? 0.f : __expf(mrun[r] - mm);
      float ps = 0.f;
      #pragma unroll
      for (int f = 0; f < 4; ++f) {
        float p = __expf(zv[f][r] - mm);
        zv[f][r] = p;
        ps += p;
      }
      ps += __shfl_xor(ps, 1);
      ps += __shfl_xor(ps, 2);
      ps += __shfl_xor(ps, 4);
      ps += __shfl_xor(ps, 8);
      lrun[r] = lrun[r] * fs + ps;
      #pragma unroll
      for (int f = 0; f < 4; ++f) O[f][r] *= fs;
      mrun[r] = mv;
    }

    char* pw = (char*)Pl + w * 2048;
    #pragma unroll
    for (int r = 0; r < 4; ++r) {
      int rowr = (lane >> 4) * 4 + r;
      int rswz = (rowr & 7) << 4;
      #pragma unroll
      for (int f = 0; f < 4; ++f) {
        int addr = (rowr * 128 + (f * 16 + col) * 2) ^ rswz;
        *(unsigned short*)(pw + addr) = f2bf(zv[f][r]);
      }
    }

    #pragma unroll
    for (int ks = 0; ks < 2; ++ks) {
      int pbyte = (col * 128 + (kgrp + ks * 32) * 2) ^ ((col & 7) << 4);
      short8 pa = *(const short8*)(pw + pbyte);
      #pragma unroll
      for (int f = 0; f < 4; ++f) {
        const unsigned short* vb = Vst + ((size_t)(bh << 6) + f * 16 + col) * NSP
                                   + s0 + kgrp + ks * 32;
        short8 bv = *(const short8*)vb;
        O[f] = __builtin_amdgcn_mfma_f32_16x16x32_bf16(pa, bv, O[f], 0, 0, 0);
      }
    }
  }

  // ---- tail term ----
  float ztail;
  {
    int trow = lane >> 2;
    int t = t0 + w * 16 + trow;
    int d0 = (lane & 3) * 16;
    const float* qr = qkv + (size_t)(b * T_ + t) * QKV_LD + h * HS_ + d0;
    float qv[16];
    #pragma unroll
    for (int j = 0; j < 4; ++j) {
      float4 v = *(const float4*)(qr + j * 4);
      qv[j*4+0] = v.x; qv[j*4+1] = v.y; qv[j*4+2] = v.z; qv[j*4+3] = v.w;
    }
    int lt = t & ~7;
    const float* kc1 = kcum + ((size_t)bh * T_ + t) * HS_ + d0;
    float kt[16];
    if (lt > 0) {
      const float* kc0 = kcum + ((size_t)bh * T_ + (lt - 1)) * HS_ + d0;
      #pragma unroll
      for (int j = 0; j < 16; ++j) kt[j] = kc1[j] - kc0[j];
    } else {
      #pragma unroll
      for (int j = 0; j < 16; ++j) kt[j] = kc1[j];
    }
    float z = 0.f;
    #pragma unroll
    for (int j = 0; j < 16; ++j) {
      float qp = qv[j] > 0.f ? qv[j] + 1.f : __expf(qv[j]);
      z += qp * kt[j];
    }
    z += __shfl_xor(z, 1);
    z += __shfl_xor(z, 2);
    ztail = z * scale;
  }

  #pragma unroll
  for (int r = 0; r < 4; ++r) {
    float zt = __shfl(ztail, ((lane >> 4) * 4 + r) * 4);
    float mv = fmaxf(mrun[r], zt);
    float fs = (mrun[r] == -INFINITY) ? 0.f : __expf(mrun[r] - mv);
    float pwgt = __expf(zt - mv);
    lrun[r] = lrun[r] * fs + pwgt;
    int tr = rows[r];
    int ltr = tr & ~7;
    #pragma unroll
    for (int f = 0; f < 4; ++f) {
      int d = f * 16 + col;
      float v1 = vcum[((size_t)bh * T_ + tr) * HS_ + d];
      float vt = (ltr > 0) ? v1 - vcum[((size_t)bh * T_ + (ltr - 1)) * HS_ + d] : v1;
      O[f][r] = O[f][r] * fs + pwgt * vt;
    }
  }

  #pragma unroll
  for (int r = 0; r < 4; ++r) {
    float inv = 1.f / lrun[r];
    unsigned short* orow = attnb + (size_t)(b * T_ + rows[r]) * CD + h * HS_;
    #pragma unroll
    for (int f = 0; f < 4; ++f)
      orow[f * 16 + col] = f2bf(O[f][r] * inv);
  }
}

// --------------------------------------------------------------------------
extern "C" void kernel_launch(void* const* d_in, const int* in_sizes, int n_in,
                              void* d_out, int out_size, void* d_ws, size_t ws_size,
                              hipStream_t stream) {
  const float* x  = (const float*)d_in[0];   // [B,T,C]
  const float* Wa = (const float*)d_in[1];   // [3C,C]
  const float* Wp = (const float*)d_in[2];   // [C,C]
  float* out = (float*)d_out;                // [B,T,C]

  char* ws = (char*)d_ws;
  size_t off = 0;
  auto alloc = [&](size_t bytes) -> char* {
    char* p = ws + off;
    off += (bytes + 255) & ~(size_t)255;
    return p;
  };

  const int M = B_ * T_;                     // 4096
  float* qkv  = (float*)alloc((size_t)M * QKV_LD * 4);            // 50.3 MB
  float* kcum = (float*)alloc((size_t)B_ * NH_ * T_ * HS_ * 4);   // 16.8 MB
  float* vcum = (float*)alloc((size_t)B_ * NH_ * T_ * HS_ * 4);   // 16.8 MB
  float* part = (float*)alloc((size_t)B_ * 32 * 2048 * 4);        // 0.5 MB
  unsigned short* wph = (unsigned short*)alloc((size_t)CD * CD * 2);

  // regionA: x_hi/x_lo (live through gemm1), then sorted set arrays
  char* regionA = alloc((size_t)16777216);
  unsigned short* xh = (unsigned short*)regionA;
  unsigned short* xl = (unsigned short*)(regionA + (size_t)M * CD * 2);
  const size_t SETS_ELEMS = (size_t)B_ * NH_ * NSP * HS_;          // 2M
  unsigned short* Ksh = (unsigned short*)regionA;                  // 4 MB
  unsigned short* Ksl = Ksh + SETS_ELEMS;                          // 4 MB
  float*          Vss = (float*)(regionA + 2 * SETS_ELEMS * 2);    // 8 MB
  unsigned short* Vst = (unsigned short*)(regionA + 2 * SETS_ELEMS * 2 + SETS_ELEMS * 4);
  int*            r_srt = (int*)(regionA + 2 * SETS_ELEMS * 2 + SETS_ELEMS * 4 + SETS_ELEMS * 2);

  // regionB: Wa_hi/Wa_lo (live through gemm1), then attn bf16 output
  char* regionB = alloc((size_t)12582912);
  unsigned short* wah = (unsigned short*)regionB;
  unsigned short* wal = (unsigned short*)(regionB + (size_t)3 * CD * CD * 2);
  unsigned short* attnb = (unsigned short*)regionB;

  // K1: splits
  split_kernel<<<dim3((M * CD) / 256), dim3(256), 0, stream>>>(x, xh, xl, M * CD);
  split_kernel<<<dim3((3 * CD * CD) / 256), dim3(256), 0, stream>>>(Wa, wah, wal, 3 * CD * CD);
  split_kernel<<<dim3((CD * CD) / 256), dim3(256), 0, stream>>>(Wp, wph, (unsigned short*)nullptr, CD * CD);

  // K2: qkv = x @ Wa^T  (split-bf16, ~f32 precision)
  gemm_bt<1><<<dim3((QKV_LD / 128) * (M / 128)), dim3(256), 0, stream>>>(
      xh, xl, wah, wal, qkv, M, QKV_LD, CD);

  // K3: phi + cumsums (coalesced 3-phase)
  cs_part<<<dim3(B_ * 32 * 2), dim3(256), 0, stream>>>(qkv, part);
  cs_prefix<<<dim3(B_ * 2048 / 256), dim3(256), 0, stream>>>(part);
  cs_final<<<dim3(B_ * 32 * 2), dim3(256), 0, stream>>>(qkv, part, kcum, vcum);

  // K4: sorted set aggregates (reuses regionA — xh/xl dead after gemm1)
  build_sets<<<dim3((B_ * NH_ * NSP * HS_) / 256), dim3(256), 0, stream>>>(
      kcum, vcum, Ksh, Ksl, Vss, r_srt);
  vst_transpose<<<dim3(B_ * NH_ * (NSP / 64)), dim3(256), 0, stream>>>(Vss, Vst);

  // K5: MFMA attention (writes bf16 into regionB — wah/wal dead after gemm1)
  attn_mfma<<<dim3(B_ * NH_ * (T_ / 64)), dim3(256), 0, stream>>>(
      qkv, kcum, vcum, Ksh, Ksl, Vst, r_srt, attnb);

  // K7: out = attn @ Wp^T
  gemm_bt<0><<<dim3((CD / 128) * (M / 128)), dim3(256), 0, stream>>>(
      attnb, (const unsigned short*)nullptr, wph, (const unsigned short*)nullptr,
      out, M, CD, CD);
}

// Round 4
// 256.297 us; speedup vs baseline: 4.2946x; 1.1039x over previous
//
#include <hip/hip_runtime.h>
#include <hip/hip_bf16.h>
#include <stdint.h>

// Problem constants (B,T,C,NH,LEVEL) = (2,2048,1024,16,3)
#define B_    2
#define T_    2048
#define CD    1024
#define NH_   16
#define HS_   64
#define NSETS 511        // sum_{l=3..11} 2048>>l
#define NSP   512        // padded
#define QKV_LD 3072
#define NEGBIG (-3.4e38f)

typedef __attribute__((ext_vector_type(8))) short  short8;
typedef __attribute__((ext_vector_type(4))) float  f32x4;

__device__ __forceinline__ unsigned short f2bf(float f) {
  unsigned u = __float_as_uint(f);
  unsigned r = 0x7FFFu + ((u >> 16) & 1u);   // round-to-nearest-even
  return (unsigned short)((u + r) >> 16);
}
__device__ __forceinline__ float bf2f(unsigned short h) {
  return __uint_as_float(((unsigned)h) << 16);
}
__device__ __forceinline__ float elu1(float x) {  // elu(x)+1
  return x > 0.f ? x + 1.f : __expf(x);
}
__device__ __forceinline__ void gload16(const unsigned short* g, short* l) {
  __builtin_amdgcn_global_load_lds(
      (const __attribute__((address_space(1))) unsigned int*)g,
      (__attribute__((address_space(3))) unsigned int*)l, 16, 0, 0);
}

// ---------------- K1: f32 -> bf16 hi (+ optional lo residual) -------------
__global__ void split_kernel(const float* __restrict__ src,
                             unsigned short* __restrict__ hi,
                             unsigned short* __restrict__ lo, int n) {
  int i = blockIdx.x * 256 + threadIdx.x;
  if (i >= n) return;
  float v = src[i];
  unsigned short h = f2bf(v);
  hi[i] = h;
  if (lo) lo[i] = f2bf(v - bf2f(h));
}

// ---------------- K2/K7: C[M,N] = A[M,K] * B[N,K]^T  (bf16 MFMA) ----------
// m97 structure: global_load_lds width=16 staging, 2-barrier K-loop.
// LDS layout: [tile][row][32 shorts], 64B rows, chunk-XOR swizzle c^(row&3)
// applied on BOTH the global source (pre-swizzle) and the ds_read address.
template<int SPLIT>
__global__ __launch_bounds__(256) void gemm_bt(
    const unsigned short* __restrict__ Ah, const unsigned short* __restrict__ Al,
    const unsigned short* __restrict__ Bh, const unsigned short* __restrict__ Bl,
    float* __restrict__ Cmat, int M, int N, int K)
{
  constexpr int NT = SPLIT ? 4 : 2;
  __shared__ short lds[NT * 4096];                   // 8KB per tile

  // XCD-aware bijective swizzle (grid %8 == 0 for both instantiations)
  const int nwg = gridDim.x;
  const int cpx = nwg >> 3;
  const int bid = blockIdx.x;
  const int swb = (bid & 7) * cpx + (bid >> 3);
  const int nbx = N >> 7;
  const int bx = swb % nbx;
  const int by = swb / nbx;

  const int row0 = by * 128;
  const int col0 = bx * 128;
  const int tid  = threadIdx.x;
  const int lane = tid & 63;
  const int w    = tid >> 6;
  const int wr   = w >> 1, wc = w & 1;

  f32x4 acc[4][4];
  #pragma unroll
  for (int a = 0; a < 4; ++a)
    #pragma unroll
    for (int b = 0; b < 4; ++b)
      acc[a][b] = (f32x4){0.f, 0.f, 0.f, 0.f};

  const int rlane = lane & 15;
  const int kgrp  = lane >> 4;                       // 0..3 (16B chunk)
  const int rsw   = (kgrp ^ (rlane & 3)) << 4;       // read-side swizzled chunk byte

  // staging: each wave owns tile(s); lane l -> row l>>2, chunk l&3 (linear LDS)
  const int slr = lane >> 2;                         // row within 16-row block
  const int sch = (lane & 3) ^ (slr & 3);            // pre-swizzled source chunk

  const unsigned short* ssrc;
  size_t srb;
  short* sbase;
  if (SPLIT) {
    ssrc = (w == 0) ? Ah : (w == 1) ? Bh : (w == 2) ? Al : Bl;
    srb  = (w & 1) ? (size_t)col0 : (size_t)row0;
    sbase = &lds[w * 4096];
  } else {
    ssrc = (w & 1) ? Bh : Ah;
    srb  = (w & 1) ? (size_t)col0 : (size_t)row0;
    sbase = &lds[(w & 1) * 4096 + (w >> 1) * 2048];  // half-tile per wave
    srb += (size_t)(w >> 1) * 64;
  }

  for (int kt = 0; kt < K; kt += 32) {
    __syncthreads();
    const unsigned short* g0 = ssrc + (srb + slr) * K + kt + (sch << 3);
    if (SPLIT) {
      #pragma unroll
      for (int i = 0; i < 8; ++i)
        gload16(g0 + (size_t)i * 16 * K, sbase + i * 512);
    } else {
      #pragma unroll
      for (int i = 0; i < 4; ++i)
        gload16(g0 + (size_t)i * 16 * K, sbase + i * 512);
    }
    __syncthreads();   // compiler drains vmcnt(0) here

    short8 aH[4], bH[4], aL[4], bL[4];
    #pragma unroll
    for (int m = 0; m < 4; ++m) {
      int r    = wr * 64 + m * 16 + rlane;
      int cidx = wc * 64 + m * 16 + rlane;
      aH[m] = *(const short8*)((const char*)lds + r * 64 + rsw);
      bH[m] = *(const short8*)((const char*)lds + 8192 + cidx * 64 + rsw);
      if (SPLIT) {
        aL[m] = *(const short8*)((const char*)lds + 16384 + r * 64 + rsw);
        bL[m] = *(const short8*)((const char*)lds + 24576 + cidx * 64 + rsw);
      }
    }
    #pragma unroll
    for (int mm = 0; mm < 4; ++mm)
      #pragma unroll
      for (int nn = 0; nn < 4; ++nn) {
        acc[mm][nn] = __builtin_amdgcn_mfma_f32_16x16x32_bf16(aH[mm], bH[nn], acc[mm][nn], 0, 0, 0);
        if (SPLIT) {
          acc[mm][nn] = __builtin_amdgcn_mfma_f32_16x16x32_bf16(aH[mm], bL[nn], acc[mm][nn], 0, 0, 0);
          acc[mm][nn] = __builtin_amdgcn_mfma_f32_16x16x32_bf16(aL[mm], bH[nn], acc[mm][nn], 0, 0, 0);
        }
      }
  }

  const int rl = (lane >> 4) * 4;
  const int cl = lane & 15;
  #pragma unroll
  for (int mm = 0; mm < 4; ++mm)
    #pragma unroll
    for (int nn = 0; nn < 4; ++nn)
      #pragma unroll
      for (int r = 0; r < 4; ++r) {
        int row = row0 + wr * 64 + mm * 16 + rl + r;
        int col = col0 + wc * 64 + nn * 16 + cl;
        Cmat[(size_t)row * N + col] = acc[mm][nn][r];
      }
}

// ---------------- K3a: per-seg partial sums (coalesced float4 columns) ----
__global__ __launch_bounds__(256) void cs_part(const float* __restrict__ qkv,
                                               float* __restrict__ part) {
  int blk = blockIdx.x;                 // B*32*2
  int q   = blk & 1;
  int seg = (blk >> 1) & 31;
  int b   = blk >> 6;
  int c   = threadIdx.x * 4;            // 0..1023
  const float* src = qkv + (size_t)(b * T_ + seg * 64) * QKV_LD + CD + q * CD + c;
  float4 s = {0.f, 0.f, 0.f, 0.f};
  #pragma unroll 4
  for (int j = 0; j < 64; ++j) {
    float4 v = *(const float4*)(src + (size_t)j * QKV_LD);
    if (q == 0) {
      s.x += elu1(v.x); s.y += elu1(v.y); s.z += elu1(v.z); s.w += elu1(v.w);
    } else {
      s.x += v.x; s.y += v.y; s.z += v.z; s.w += v.w;
    }
  }
  *(float4*)(part + ((size_t)(b * 32 + seg) * 2048) + q * 1024 + c) = s;
}

// ---------------- K3b: exclusive prefix over 32 segs per column ----------
__global__ void cs_prefix(float* __restrict__ part) {
  int idx = blockIdx.x * 256 + threadIdx.x;      // B*2048
  int b  = idx >> 11;
  int cc = idx & 2047;
  float run = 0.f;
  #pragma unroll 8
  for (int s = 0; s < 32; ++s) {
    size_t o = (size_t)(b * 32 + s) * 2048 + cc;
    float t = part[o];
    part[o] = run;
    run += t;
  }
}

// ---------------- K3c: final walk -> kcum / vcum --------------------------
__global__ __launch_bounds__(256) void cs_final(const float* __restrict__ qkv,
                                                const float* __restrict__ part,
                                                float* __restrict__ kcum,
                                                float* __restrict__ vcum) {
  int blk = blockIdx.x;
  int q   = blk & 1;
  int seg = (blk >> 1) & 31;
  int b   = blk >> 6;
  int c   = threadIdx.x * 4;
  int h   = c >> 6, d = c & 63;
  const float* src = qkv + (size_t)(b * T_ + seg * 64) * QKV_LD + CD + q * CD + c;
  float* dst = (q == 0 ? kcum : vcum) + ((size_t)(b * NH_ + h) * T_ + seg * 64) * HS_ + d;
  float4 s = *(const float4*)(part + ((size_t)(b * 32 + seg) * 2048) + q * 1024 + c);
  #pragma unroll 4
  for (int j = 0; j < 64; ++j) {
    float4 v = *(const float4*)(src + (size_t)j * QKV_LD);
    if (q == 0) {
      s.x += elu1(v.x); s.y += elu1(v.y); s.z += elu1(v.z); s.w += elu1(v.w);
    } else {
      s.x += v.x; s.y += v.y; s.z += v.z; s.w += v.w;
    }
    *(float4*)(dst + (size_t)j * HS_) = s;
  }
}

// ---------------- K4: sorted-by-r set aggregates ---------------------------
__global__ void build_sets(const float* __restrict__ kcum, const float* __restrict__ vcum,
                           unsigned short* __restrict__ Ksh, unsigned short* __restrict__ Ksl,
                           float* __restrict__ Vs, int* __restrict__ r_srt) {
  int idx = blockIdx.x * 256 + threadIdx.x;    // B*NH*512*64
  if (idx >= B_ * NH_ * NSP * HS_) return;
  int d  = idx & 63;
  int s  = (idx >> 6) & (NSP - 1);
  int bh = idx >> (6 + 9);
  if (s == NSETS) {                            // padding entry
    size_t o = ((size_t)(bh << 9) + s) * HS_ + d;
    Ksh[o] = 0; Ksl[o] = 0; Vs[o] = 0.f;
    if (bh == 0 && d == 0) r_srt[s] = 0x7fffffff;
    return;
  }
  int lvl = 3, base = 0;
  while (s >= base + (T_ >> lvl)) { base += T_ >> lvl; ++lvl; }
  int i  = s - base;
  int m  = (i + 1) << lvl;
  int r  = m - 1;
  int li = i << lvl;
  int rank = lvl - 3;
  #pragma unroll
  for (int j = 3; j <= 11; ++j) rank += (m - 8) >> j;

  size_t rowr = ((size_t)bh * T_ + r) * HS_ + d;
  float kr = kcum[rowr], vr = vcum[rowr];
  if (li > 0) {
    size_t rowl = ((size_t)bh * T_ + li - 1) * HS_ + d;
    kr -= kcum[rowl];
    vr -= vcum[rowl];
  }
  size_t o = ((size_t)(bh << 9) + rank) * HS_ + d;
  unsigned short kh = f2bf(kr);
  Ksh[o] = kh;
  Ksl[o] = f2bf(kr - bf2f(kh));
  Vs[o]  = vr;
  if (bh == 0 && d == 0) r_srt[rank] = r;
}

// ---------------- K4b: Vst[bh][d][512] bf16 = transpose(Vs) ---------------
__global__ __launch_bounds__(256) void vst_transpose(
    const float* __restrict__ Vs, unsigned short* __restrict__ Vst) {
  __shared__ float tile[64][65];
  int bh = blockIdx.x >> 3;
  int s0 = (blockIdx.x & 7) * 64;
  int tid = threadIdx.x;
  int srow = tid >> 2, c0 = (tid & 3) * 16;
  const float* src = Vs + ((size_t)(bh << 9) + s0 + srow) * HS_ + c0;
  #pragma unroll
  for (int j = 0; j < 4; ++j) {
    float4 v = *(const float4*)(src + j * 4);
    tile[srow][c0 + j*4 + 0] = v.x; tile[srow][c0 + j*4 + 1] = v.y;
    tile[srow][c0 + j*4 + 2] = v.z; tile[srow][c0 + j*4 + 3] = v.w;
  }
  __syncthreads();
  int d = tid >> 2, sq = (tid & 3) * 16;
  short8 a, b;
  #pragma unroll
  for (int j = 0; j < 8; ++j) {
    a[j] = (short)f2bf(tile[sq + j][d]);
    b[j] = (short)f2bf(tile[sq + 8 + j][d]);
  }
  unsigned short* dst = Vst + ((size_t)(bh << 6) + d) * NSP + s0 + sq;
  *(short8*)dst = a;
  *(short8*)(dst + 8) = b;
}

// ---------------- K5: MFMA flash attention over sorted sets ---------------
// Block mapping: XCD-grouped bh (4 bh per XCD, K/V L2-resident) with
// tch-balanced spread within XCD (CU gets tch {c,c+8,c+16,c+24}).
// Softmax: defer-max (THR=8) via in-lane max + __all ballot; cross-lane sum
// fully deferred to epilogue (lane-local lsum partials).
__global__ __launch_bounds__(256) void attn_mfma(
    const float* __restrict__ qkv, const float* __restrict__ kcum,
    const float* __restrict__ vcum,
    const unsigned short* __restrict__ Ksh, const unsigned short* __restrict__ Ksl,
    const unsigned short* __restrict__ Vst, const int* __restrict__ r_srt,
    unsigned short* __restrict__ attnb)
{
  __shared__ short Qh[64 * 64];
  __shared__ short Ql[64 * 64];
  __shared__ short Pl[4 * 16 * 64];
  __shared__ int   rs_lds[NSP];

  const int blk = blockIdx.x;           // 1024
  const int xcd = blk & 7;
  const int j   = blk >> 3;             // 0..127
  const int bh  = xcd * 4 + (j >> 5);
  const int tch = (j + ((j >> 5) << 3)) & 31;
  const int b = bh >> 4, h = bh & 15;
  const int t0 = tch * 64;
  const int tid = threadIdx.x;
  const int lane = tid & 63;
  const int w = tid >> 6;
  const int col = lane & 15;
  const float scale = 0.125f;

  // ---- Phase 1: load Q tile f32, split to bf16 hi/lo, swizzled LDS ----
  {
    int row = tid >> 2;
    int d0  = (tid & 3) * 16;
    const float* qr = qkv + (size_t)(b * T_ + t0 + row) * QKV_LD + h * HS_ + d0;
    float qv[16];
    #pragma unroll
    for (int jj = 0; jj < 4; ++jj) {
      float4 v = *(const float4*)(qr + jj * 4);
      qv[jj*4+0] = v.x; qv[jj*4+1] = v.y; qv[jj*4+2] = v.z; qv[jj*4+3] = v.w;
    }
    short8 hh[2], ll[2];
    #pragma unroll
    for (int c = 0; c < 2; ++c)
      #pragma unroll
      for (int jj = 0; jj < 8; ++jj) {
        float f = qv[c*8+jj];
        unsigned short hi = f2bf(f);
        hh[c][jj] = (short)hi;
        ll[c][jj] = (short)f2bf(f - bf2f(hi));
      }
    int swz = (row & 7) << 4;
    #pragma unroll
    for (int c = 0; c < 2; ++c) {
      int addr = (row * 128 + d0 * 2 + c * 16) ^ swz;
      *(short8*)((char*)Qh + addr) = hh[c];
      *(short8*)((char*)Ql + addr) = ll[c];
    }
    for (int s = tid; s < NSP; s += 256) rs_lds[s] = r_srt[s];
  }
  __syncthreads();

  int rows[4];
  #pragma unroll
  for (int r = 0; r < 4; ++r) rows[r] = t0 + w * 16 + (lane >> 4) * 4 + r;

  f32x4 O[4];
  #pragma unroll
  for (int f = 0; f < 4; ++f) O[f] = (f32x4){0.f, 0.f, 0.f, 0.f};
  float mrun[4] = {NEGBIG, NEGBIG, NEGBIG, NEGBIG};
  float lsum[4] = {0.f, 0.f, 0.f, 0.f};

  int nmax = 0;
  #pragma unroll
  for (int jj = 3; jj <= 11; ++jj) nmax += (t0 + 64) >> jj;
  const int ntiles = (nmax + 63) >> 6;

  const int arow  = w * 16 + col;
  const int aswz  = (arow & 7) << 4;
  const int kgrp  = (lane >> 4) * 8;

  for (int tile = 0; tile < ntiles; ++tile) {
    const int s0 = tile * 64;
    f32x4 S[4];
    #pragma unroll
    for (int f = 0; f < 4; ++f) S[f] = (f32x4){0.f, 0.f, 0.f, 0.f};

    #pragma unroll
    for (int ks = 0; ks < 2; ++ks) {
      int abyte = (arow * 128 + (kgrp + ks * 32) * 2) ^ aswz;
      short8 aH = *(const short8*)((const char*)Qh + abyte);
      short8 aL = *(const short8*)((const char*)Ql + abyte);
      #pragma unroll
      for (int f = 0; f < 4; ++f) {
        size_t ko = ((size_t)(bh << 9) + s0 + f * 16 + col) * HS_ + kgrp + ks * 32;
        short8 bHv = *(const short8*)(Ksh + ko);
        short8 bLv = *(const short8*)(Ksl + ko);
        S[f] = __builtin_amdgcn_mfma_f32_16x16x32_bf16(aH, bHv, S[f], 0, 0, 0);
        S[f] = __builtin_amdgcn_mfma_f32_16x16x32_bf16(aH, bLv, S[f], 0, 0, 0);
        S[f] = __builtin_amdgcn_mfma_f32_16x16x32_bf16(aL, bHv, S[f], 0, 0, 0);
      }
    }

    int rsv[4];
    #pragma unroll
    for (int f = 0; f < 4; ++f) rsv[f] = rs_lds[s0 + f * 16 + col];

    float zv[4][4];
    #pragma unroll
    for (int f = 0; f < 4; ++f)
      #pragma unroll
      for (int r = 0; r < 4; ++r)
        zv[f][r] = (rsv[f] > rows[r]) ? NEGBIG : S[f][r] * scale;

    // ---- fast-path check: all logits within mrun+8 ? ----
    float mx[4];
    #pragma unroll
    for (int r = 0; r < 4; ++r)
      mx[r] = fmaxf(fmaxf(zv[0][r], zv[1][r]), fmaxf(zv[2][r], zv[3][r]));
    int pred = (mx[0] <= mrun[0] + 8.f) & (mx[1] <= mrun[1] + 8.f) &
               (mx[2] <= mrun[2] + 8.f) & (mx[3] <= mrun[3] + 8.f);
    if (!__all(pred)) {
      // slow path: per-row 16-lane max reduce + consistent rescale
      #pragma unroll
      for (int r = 0; r < 4; ++r) {
        float mt = mx[r];
        mt = fmaxf(mt, __shfl_xor(mt, 1));
        mt = fmaxf(mt, __shfl_xor(mt, 2));
        mt = fmaxf(mt, __shfl_xor(mt, 4));
        mt = fmaxf(mt, __shfl_xor(mt, 8));
        float mv = fmaxf(mrun[r], mt);
        float fs = __expf(mrun[r] - mv);      // NEGBIG-NEGBIG=0 -> 1 (state is 0 anyway)
        lsum[r] *= fs;
        #pragma unroll
        for (int f = 0; f < 4; ++f) O[f][r] *= fs;
        mrun[r] = mv;
      }
    }

    // ---- P = exp(z - mrun), masked; lane-local sum; write bf16 to LDS ----
    char* pw = (char*)Pl + w * 2048;
    #pragma unroll
    for (int r = 0; r < 4; ++r) {
      int rowr = (lane >> 4) * 4 + r;
      int rswz = (rowr & 7) << 4;
      #pragma unroll
      for (int f = 0; f < 4; ++f) {
        float p = __expf(zv[f][r] - mrun[r]);
        p = (rsv[f] > rows[r]) ? 0.f : p;
        lsum[r] += p;
        int addr = (rowr * 128 + (f * 16 + col) * 2) ^ rswz;
        *(unsigned short*)(pw + addr) = f2bf(p);
      }
    }

    #pragma unroll
    for (int ks = 0; ks < 2; ++ks) {
      int pbyte = (col * 128 + (kgrp + ks * 32) * 2) ^ ((col & 7) << 4);
      short8 pa = *(const short8*)(pw + pbyte);
      #pragma unroll
      for (int f = 0; f < 4; ++f) {
        const unsigned short* vb = Vst + ((size_t)(bh << 6) + f * 16 + col) * NSP
                                   + s0 + kgrp + ks * 32;
        short8 bv = *(const short8*)vb;
        O[f] = __builtin_amdgcn_mfma_f32_16x16x32_bf16(pa, bv, O[f], 0, 0, 0);
      }
    }
  }

  // ---- deferred cross-lane sum of lsum -> lrun ----
  float lrun[4];
  #pragma unroll
  for (int r = 0; r < 4; ++r) {
    float l = lsum[r];
    l += __shfl_xor(l, 1);
    l += __shfl_xor(l, 2);
    l += __shfl_xor(l, 4);
    l += __shfl_xor(l, 8);
    lrun[r] = l;
  }

  // ---- tail term: interval [t&~7, t] with q_phi, per-row VALU ----
  float ztail;
  {
    int trow = lane >> 2;
    int t = t0 + w * 16 + trow;
    int d0 = (lane & 3) * 16;
    const float* qr = qkv + (size_t)(b * T_ + t) * QKV_LD + h * HS_ + d0;
    float qv[16];
    #pragma unroll
    for (int jj = 0; jj < 4; ++jj) {
      float4 v = *(const float4*)(qr + jj * 4);
      qv[jj*4+0] = v.x; qv[jj*4+1] = v.y; qv[jj*4+2] = v.z; qv[jj*4+3] = v.w;
    }
    int lt = t & ~7;
    const float* kc1 = kcum + ((size_t)bh * T_ + t) * HS_ + d0;
    float kt[16];
    if (lt > 0) {
      const float* kc0 = kcum + ((size_t)bh * T_ + (lt - 1)) * HS_ + d0;
      #pragma unroll
      for (int jj = 0; jj < 16; ++jj) kt[jj] = kc1[jj] - kc0[jj];
    } else {
      #pragma unroll
      for (int jj = 0; jj < 16; ++jj) kt[jj] = kc1[jj];
    }
    float z = 0.f;
    #pragma unroll
    for (int jj = 0; jj < 16; ++jj) {
      float qp = qv[jj] > 0.f ? qv[jj] + 1.f : __expf(qv[jj]);
      z += qp * kt[jj];
    }
    z += __shfl_xor(z, 1);
    z += __shfl_xor(z, 2);
    ztail = z * scale;
  }

  #pragma unroll
  for (int r = 0; r < 4; ++r) {
    float zt = __shfl(ztail, ((lane >> 4) * 4 + r) * 4);
    float mv = fmaxf(mrun[r], zt);
    float fs = __expf(mrun[r] - mv);           // mrun=NEGBIG -> 0
    float pwgt = __expf(zt - mv);
    lrun[r] = lrun[r] * fs + pwgt;
    int tr = rows[r];
    int ltr = tr & ~7;
    #pragma unroll
    for (int f = 0; f < 4; ++f) {
      int d = f * 16 + col;
      float v1 = vcum[((size_t)bh * T_ + tr) * HS_ + d];
      float vt = (ltr > 0) ? v1 - vcum[((size_t)bh * T_ + (ltr - 1)) * HS_ + d] : v1;
      O[f][r] = O[f][r] * fs + pwgt * vt;
    }
  }

  #pragma unroll
  for (int r = 0; r < 4; ++r) {
    float inv = 1.f / lrun[r];
    unsigned short* orow = attnb + (size_t)(b * T_ + rows[r]) * CD + h * HS_;
    #pragma unroll
    for (int f = 0; f < 4; ++f)
      orow[f * 16 + col] = f2bf(O[f][r] * inv);
  }
}

// --------------------------------------------------------------------------
extern "C" void kernel_launch(void* const* d_in, const int* in_sizes, int n_in,
                              void* d_out, int out_size, void* d_ws, size_t ws_size,
                              hipStream_t stream) {
  const float* x  = (const float*)d_in[0];   // [B,T,C]
  const float* Wa = (const float*)d_in[1];   // [3C,C]
  const float* Wp = (const float*)d_in[2];   // [C,C]
  float* out = (float*)d_out;                // [B,T,C]

  char* ws = (char*)d_ws;
  size_t off = 0;
  auto alloc = [&](size_t bytes) -> char* {
    char* p = ws + off;
    off += (bytes + 255) & ~(size_t)255;
    return p;
  };

  const int M = B_ * T_;                     // 4096
  float* qkv  = (float*)alloc((size_t)M * QKV_LD * 4);            // 50.3 MB
  float* kcum = (float*)alloc((size_t)B_ * NH_ * T_ * HS_ * 4);   // 16.8 MB
  float* vcum = (float*)alloc((size_t)B_ * NH_ * T_ * HS_ * 4);   // 16.8 MB
  float* part = (float*)alloc((size_t)B_ * 32 * 2048 * 4);        // 0.5 MB
  unsigned short* wph = (unsigned short*)alloc((size_t)CD * CD * 2);

  // regionA: x_hi/x_lo (live through gemm1), then sorted set arrays
  char* regionA = alloc((size_t)16777216);
  unsigned short* xh = (unsigned short*)regionA;
  unsigned short* xl = (unsigned short*)(regionA + (size_t)M * CD * 2);
  const size_t SETS_ELEMS = (size_t)B_ * NH_ * NSP * HS_;          // 2M
  unsigned short* Ksh = (unsigned short*)regionA;                  // 4 MB
  unsigned short* Ksl = Ksh + SETS_ELEMS;                          // 4 MB
  float*          Vss = (float*)(regionA + 2 * SETS_ELEMS * 2);    // 8 MB
  unsigned short* Vst = (unsigned short*)(regionA + 2 * SETS_ELEMS * 2 + SETS_ELEMS * 4);
  int*            r_srt = (int*)(regionA + 2 * SETS_ELEMS * 2 + SETS_ELEMS * 4 + SETS_ELEMS * 2);

  // regionB: Wa_hi/Wa_lo (live through gemm1), then attn bf16 output
  char* regionB = alloc((size_t)12582912);
  unsigned short* wah = (unsigned short*)regionB;
  unsigned short* wal = (unsigned short*)(regionB + (size_t)3 * CD * CD * 2);
  unsigned short* attnb = (unsigned short*)regionB;

  // K1: splits
  split_kernel<<<dim3((M * CD) / 256), dim3(256), 0, stream>>>(x, xh, xl, M * CD);
  split_kernel<<<dim3((3 * CD * CD) / 256), dim3(256), 0, stream>>>(Wa, wah, wal, 3 * CD * CD);
  split_kernel<<<dim3((CD * CD) / 256), dim3(256), 0, stream>>>(Wp, wph, (unsigned short*)nullptr, CD * CD);

  // K2: qkv = x @ Wa^T  (split-bf16, ~f32 precision)
  gemm_bt<1><<<dim3((QKV_LD / 128) * (M / 128)), dim3(256), 0, stream>>>(
      xh, xl, wah, wal, qkv, M, QKV_LD, CD);

  // K3: phi + cumsums (coalesced 3-phase)
  cs_part<<<dim3(B_ * 32 * 2), dim3(256), 0, stream>>>(qkv, part);
  cs_prefix<<<dim3(B_ * 2048 / 256), dim3(256), 0, stream>>>(part);
  cs_final<<<dim3(B_ * 32 * 2), dim3(256), 0, stream>>>(qkv, part, kcum, vcum);

  // K4: sorted set aggregates (reuses regionA — xh/xl dead after gemm1)
  build_sets<<<dim3((B_ * NH_ * NSP * HS_) / 256), dim3(256), 0, stream>>>(
      kcum, vcum, Ksh, Ksl, Vss, r_srt);
  vst_transpose<<<dim3(B_ * NH_ * (NSP / 64)), dim3(256), 0, stream>>>(Vss, Vst);

  // K5: MFMA attention (writes bf16 into regionB — wah/wal dead after gemm1)
  attn_mfma<<<dim3(B_ * NH_ * (T_ / 64)), dim3(256), 0, stream>>>(
      qkv, kcum, vcum, Ksh, Ksl, Vst, r_srt, attnb);

  // K7: out = attn @ Wp^T
  gemm_bt<0><<<dim3((CD / 128) * (M / 128)), dim3(256), 0, stream>>>(
      attnb, (const unsigned short*)nullptr, wph, (const unsigned short*)nullptr,
      out, M, CD, CD);
}

// Round 5
// 228.664 us; speedup vs baseline: 4.8136x; 1.1208x over previous
//
#include <hip/hip_runtime.h>
#include <hip/hip_bf16.h>
#include <stdint.h>

// Problem constants (B,T,C,NH,LEVEL) = (2,2048,1024,16,3)
#define B_    2
#define T_    2048
#define CD    1024
#define NH_   16
#define HS_   64
#define NSETS 511        // sum_{l=3..11} 2048>>l
#define NSP   512        // padded
#define QKV_LD 3072
#define NEGBIG (-3.4e38f)

typedef __attribute__((ext_vector_type(8))) short  short8;
typedef __attribute__((ext_vector_type(4))) float  f32x4;

__device__ __forceinline__ unsigned short f2bf(float f) {
  unsigned u = __float_as_uint(f);
  unsigned r = 0x7FFFu + ((u >> 16) & 1u);   // round-to-nearest-even
  return (unsigned short)((u + r) >> 16);
}
__device__ __forceinline__ float bf2f(unsigned short h) {
  return __uint_as_float(((unsigned)h) << 16);
}
__device__ __forceinline__ float elu1(float x) {  // elu(x)+1
  return x > 0.f ? x + 1.f : __expf(x);
}
__device__ __forceinline__ void gload16(const unsigned short* g, short* l) {
  __builtin_amdgcn_global_load_lds(
      (const __attribute__((address_space(1))) unsigned int*)g,
      (__attribute__((address_space(3))) unsigned int*)l, 16, 0, 0);
}

// ---------------- K1: fused splits: x->hi/lo, Wa->hi/lo, Wp->hi ----------
__global__ __launch_bounds__(256) void split3_kernel(
    const float* __restrict__ x, const float* __restrict__ Wa,
    const float* __restrict__ Wp,
    unsigned short* __restrict__ xh, unsigned short* __restrict__ xl,
    unsigned short* __restrict__ wah, unsigned short* __restrict__ wal,
    unsigned short* __restrict__ wph) {
  int bid = blockIdx.x;
  const float* src; unsigned short *hi, *lo; int base;
  if (bid < 16384)      { src = x;  hi = xh;  lo = xl;  base = bid; }
  else if (bid < 28672) { src = Wa; hi = wah; lo = wal; base = bid - 16384; }
  else                  { src = Wp; hi = wph; lo = nullptr; base = bid - 28672; }
  int i = base * 256 + threadIdx.x;
  float v = src[i];
  unsigned short h = f2bf(v);
  hi[i] = h;
  if (lo) lo[i] = f2bf(v - bf2f(h));
}

// ---------------- K2/K7: C[M,N] = A[M,K] * B[N,K]^T  (bf16 MFMA) ----------
// m97 structure: global_load_lds width=16 staging, 2-barrier K-loop.
// LDS layout: [tile][row][32 shorts], 64B rows. Chunk-XOR swizzle
// g(row) = (row&3)^((row>>2)&3) applied on BOTH the global source
// (pre-swizzle) and the ds_read address (same involution, G21).
template<int SPLIT>
__global__ __launch_bounds__(256) void gemm_bt(
    const unsigned short* __restrict__ Ah, const unsigned short* __restrict__ Al,
    const unsigned short* __restrict__ Bh, const unsigned short* __restrict__ Bl,
    float* __restrict__ Cmat, int M, int N, int K)
{
  constexpr int NT = SPLIT ? 4 : 2;
  __shared__ short lds[NT * 4096];                   // 8KB per tile

  // XCD-aware bijective swizzle (grid %8 == 0 for both instantiations)
  const int nwg = gridDim.x;
  const int cpx = nwg >> 3;
  const int bid = blockIdx.x;
  const int swb = (bid & 7) * cpx + (bid >> 3);
  const int nbx = N >> 7;
  const int bx = swb % nbx;
  const int by = swb / nbx;

  const int row0 = by * 128;
  const int col0 = bx * 128;
  const int tid  = threadIdx.x;
  const int lane = tid & 63;
  const int w    = tid >> 6;
  const int wr   = w >> 1, wc = w & 1;

  f32x4 acc[4][4];
  #pragma unroll
  for (int a = 0; a < 4; ++a)
    #pragma unroll
    for (int b = 0; b < 4; ++b)
      acc[a][b] = (f32x4){0.f, 0.f, 0.f, 0.f};

  const int rlane = lane & 15;
  const int kgrp  = lane >> 4;                       // 0..3 (16B chunk)
  const int rsw   = (kgrp ^ (rlane & 3) ^ ((rlane >> 2) & 3)) << 4;

  // staging: lane l -> row l>>2, chunk l&3 (linear LDS dest)
  const int slr = lane >> 2;                         // row within 16-row block
  const int sch = (lane & 3) ^ (slr & 3) ^ ((slr >> 2) & 3);

  const unsigned short* ssrc;
  size_t srb;
  short* sbase;
  if (SPLIT) {
    ssrc = (w == 0) ? Ah : (w == 1) ? Bh : (w == 2) ? Al : Bl;
    srb  = (w & 1) ? (size_t)col0 : (size_t)row0;
    sbase = &lds[w * 4096];
  } else {
    ssrc = (w & 1) ? Bh : Ah;
    srb  = (w & 1) ? (size_t)col0 : (size_t)row0;
    sbase = &lds[(w & 1) * 4096 + (w >> 1) * 2048];  // half-tile per wave
    srb += (size_t)(w >> 1) * 64;
  }

  for (int kt = 0; kt < K; kt += 32) {
    __syncthreads();
    const unsigned short* g0 = ssrc + (srb + slr) * K + kt + (sch << 3);
    if (SPLIT) {
      #pragma unroll
      for (int i = 0; i < 8; ++i)
        gload16(g0 + (size_t)i * 16 * K, sbase + i * 512);
    } else {
      #pragma unroll
      for (int i = 0; i < 4; ++i)
        gload16(g0 + (size_t)i * 16 * K, sbase + i * 512);
    }
    __syncthreads();   // compiler drains vmcnt(0) here

    short8 aH[4], bH[4], aL[4], bL[4];
    #pragma unroll
    for (int m = 0; m < 4; ++m) {
      int r    = wr * 64 + m * 16 + rlane;
      int cidx = wc * 64 + m * 16 + rlane;
      aH[m] = *(const short8*)((const char*)lds + r * 64 + rsw);
      bH[m] = *(const short8*)((const char*)lds + 8192 + cidx * 64 + rsw);
      if (SPLIT) {
        aL[m] = *(const short8*)((const char*)lds + 16384 + r * 64 + rsw);
        bL[m] = *(const short8*)((const char*)lds + 24576 + cidx * 64 + rsw);
      }
    }
    #pragma unroll
    for (int mm = 0; mm < 4; ++mm)
      #pragma unroll
      for (int nn = 0; nn < 4; ++nn) {
        acc[mm][nn] = __builtin_amdgcn_mfma_f32_16x16x32_bf16(aH[mm], bH[nn], acc[mm][nn], 0, 0, 0);
        if (SPLIT) {
          acc[mm][nn] = __builtin_amdgcn_mfma_f32_16x16x32_bf16(aH[mm], bL[nn], acc[mm][nn], 0, 0, 0);
          acc[mm][nn] = __builtin_amdgcn_mfma_f32_16x16x32_bf16(aL[mm], bH[nn], acc[mm][nn], 0, 0, 0);
        }
      }
  }

  const int rl = (lane >> 4) * 4;
  const int cl = lane & 15;
  #pragma unroll
  for (int mm = 0; mm < 4; ++mm)
    #pragma unroll
    for (int nn = 0; nn < 4; ++nn)
      #pragma unroll
      for (int r = 0; r < 4; ++r) {
        int row = row0 + wr * 64 + mm * 16 + rl + r;
        int col = col0 + wc * 64 + nn * 16 + cl;
        Cmat[(size_t)row * N + col] = acc[mm][nn][r];
      }
}

// ---------------- K3a: per-seg partial sums (coalesced float4 columns) ----
__global__ __launch_bounds__(256) void cs_part(const float* __restrict__ qkv,
                                               float* __restrict__ part) {
  int blk = blockIdx.x;                 // B*32*2
  int q   = blk & 1;
  int seg = (blk >> 1) & 31;
  int b   = blk >> 6;
  int c   = threadIdx.x * 4;            // 0..1023
  const float* src = qkv + (size_t)(b * T_ + seg * 64) * QKV_LD + CD + q * CD + c;
  float4 s = {0.f, 0.f, 0.f, 0.f};
  #pragma unroll 4
  for (int j = 0; j < 64; ++j) {
    float4 v = *(const float4*)(src + (size_t)j * QKV_LD);
    if (q == 0) {
      s.x += elu1(v.x); s.y += elu1(v.y); s.z += elu1(v.z); s.w += elu1(v.w);
    } else {
      s.x += v.x; s.y += v.y; s.z += v.z; s.w += v.w;
    }
  }
  *(float4*)(part + ((size_t)(b * 32 + seg) * 2048) + q * 1024 + c) = s;
}

// ---------------- K3b: exclusive prefix over 32 segs per column ----------
__global__ void cs_prefix(float* __restrict__ part) {
  int idx = blockIdx.x * 256 + threadIdx.x;      // B*2048
  int b  = idx >> 11;
  int cc = idx & 2047;
  float run = 0.f;
  #pragma unroll 8
  for (int s = 0; s < 32; ++s) {
    size_t o = (size_t)(b * 32 + s) * 2048 + cc;
    float t = part[o];
    part[o] = run;
    run += t;
  }
}

// ---------------- K3c: final walk -> kcum / vcum --------------------------
__global__ __launch_bounds__(256) void cs_final(const float* __restrict__ qkv,
                                                const float* __restrict__ part,
                                                float* __restrict__ kcum,
                                                float* __restrict__ vcum) {
  int blk = blockIdx.x;
  int q   = blk & 1;
  int seg = (blk >> 1) & 31;
  int b   = blk >> 6;
  int c   = threadIdx.x * 4;
  int h   = c >> 6, d = c & 63;
  const float* src = qkv + (size_t)(b * T_ + seg * 64) * QKV_LD + CD + q * CD + c;
  float* dst = (q == 0 ? kcum : vcum) + ((size_t)(b * NH_ + h) * T_ + seg * 64) * HS_ + d;
  float4 s = *(const float4*)(part + ((size_t)(b * 32 + seg) * 2048) + q * 1024 + c);
  #pragma unroll 4
  for (int j = 0; j < 64; ++j) {
    float4 v = *(const float4*)(src + (size_t)j * QKV_LD);
    if (q == 0) {
      s.x += elu1(v.x); s.y += elu1(v.y); s.z += elu1(v.z); s.w += elu1(v.w);
    } else {
      s.x += v.x; s.y += v.y; s.z += v.z; s.w += v.w;
    }
    *(float4*)(dst + (size_t)j * HS_) = s;
  }
}

// ---------------- K4: sorted-by-r set aggregates ---------------------------
__global__ void build_sets(const float* __restrict__ kcum, const float* __restrict__ vcum,
                           unsigned short* __restrict__ Ksh, unsigned short* __restrict__ Ksl,
                           float* __restrict__ Vs, int* __restrict__ r_srt) {
  int idx = blockIdx.x * 256 + threadIdx.x;    // B*NH*512*64
  if (idx >= B_ * NH_ * NSP * HS_) return;
  int d  = idx & 63;
  int s  = (idx >> 6) & (NSP - 1);
  int bh = idx >> (6 + 9);
  if (s == NSETS) {                            // padding entry
    size_t o = ((size_t)(bh << 9) + s) * HS_ + d;
    Ksh[o] = 0; Ksl[o] = 0; Vs[o] = 0.f;
    if (bh == 0 && d == 0) r_srt[s] = 0x7fffffff;
    return;
  }
  int lvl = 3, base = 0;
  while (s >= base + (T_ >> lvl)) { base += T_ >> lvl; ++lvl; }
  int i  = s - base;
  int m  = (i + 1) << lvl;
  int r  = m - 1;
  int li = i << lvl;
  int rank = lvl - 3;
  #pragma unroll
  for (int j = 3; j <= 11; ++j) rank += (m - 8) >> j;

  size_t rowr = ((size_t)bh * T_ + r) * HS_ + d;
  float kr = kcum[rowr], vr = vcum[rowr];
  if (li > 0) {
    size_t rowl = ((size_t)bh * T_ + li - 1) * HS_ + d;
    kr -= kcum[rowl];
    vr -= vcum[rowl];
  }
  size_t o = ((size_t)(bh << 9) + rank) * HS_ + d;
  unsigned short kh = f2bf(kr);
  Ksh[o] = kh;
  Ksl[o] = f2bf(kr - bf2f(kh));
  Vs[o]  = vr;
  if (bh == 0 && d == 0) r_srt[rank] = r;
}

// ---------------- K4b: Vst[bh][d][512] bf16 = transpose(Vs) ---------------
__global__ __launch_bounds__(256) void vst_transpose(
    const float* __restrict__ Vs, unsigned short* __restrict__ Vst) {
  __shared__ float tile[64][65];
  int bh = blockIdx.x >> 3;
  int s0 = (blockIdx.x & 7) * 64;
  int tid = threadIdx.x;
  int srow = tid >> 2, c0 = (tid & 3) * 16;
  const float* src = Vs + ((size_t)(bh << 9) + s0 + srow) * HS_ + c0;
  #pragma unroll
  for (int j = 0; j < 4; ++j) {
    float4 v = *(const float4*)(src + j * 4);
    tile[srow][c0 + j*4 + 0] = v.x; tile[srow][c0 + j*4 + 1] = v.y;
    tile[srow][c0 + j*4 + 2] = v.z; tile[srow][c0 + j*4 + 3] = v.w;
  }
  __syncthreads();
  int d = tid >> 2, sq = (tid & 3) * 16;
  short8 a, b;
  #pragma unroll
  for (int j = 0; j < 8; ++j) {
    a[j] = (short)f2bf(tile[sq + j][d]);
    b[j] = (short)f2bf(tile[sq + 8 + j][d]);
  }
  unsigned short* dst = Vst + ((size_t)(bh << 6) + d) * NSP + s0 + sq;
  *(short8*)dst = a;
  *(short8*)(dst + 8) = b;
}

// ---------------- K5: MFMA flash attention over sorted sets ---------------
// K/V tiles double-buffered in LDS via global_load_lds (2-phase prefetch,
// T3 minimum recipe). 128B LDS rows XOR-swizzled: pre-swizzled global
// source + same XOR on ds_read (G21). Defer-max softmax (THR=8).
__global__ __launch_bounds__(256) void attn_mfma(
    const float* __restrict__ qkv, const float* __restrict__ kcum,
    const float* __restrict__ vcum,
    const unsigned short* __restrict__ Ksh, const unsigned short* __restrict__ Ksl,
    const unsigned short* __restrict__ Vst, const int* __restrict__ r_srt,
    unsigned short* __restrict__ attnb)
{
  __shared__ short Qh[64 * 64];
  __shared__ short Ql[64 * 64];
  __shared__ short Pl[4 * 16 * 64];
  __shared__ short KV[2][3 * 4096];     // [dbuf][Ksh|Ksl|Vst tiles, 8KB each]
  __shared__ int   rs_lds[NSP];

  const int blk = blockIdx.x;           // 1024
  const int xcd = blk & 7;
  const int j   = blk >> 3;             // 0..127
  const int bh  = xcd * 4 + (j >> 5);
  const int tch = (j + ((j >> 5) << 3)) & 31;
  const int b = bh >> 4, h = bh & 15;
  const int t0 = tch * 64;
  const int tid = threadIdx.x;
  const int lane = tid & 63;
  const int w = tid >> 6;
  const int col = lane & 15;
  const float scale = 0.125f;

  // staging geometry: per wave 6 gload16; lane l -> row i*8+(l>>3),
  // pre-swizzled source chunk ((l&7)^(l>>3)); LDS dest linear (lane*16B)
  const int srow = lane >> 3;
  const int scsw = ((lane & 7) ^ srow) * 8;

  auto stage_tile = [&](short* kv, int s0) {
    #pragma unroll
    for (int L = w * 6; L < w * 6 + 6; ++L) {
      int a = L >> 3, i = L & 7;
      const unsigned short* src;
      if (a == 0)      src = Ksh + ((size_t)(bh << 9) + s0 + i * 8 + srow) * 64 + scsw;
      else if (a == 1) src = Ksl + ((size_t)(bh << 9) + s0 + i * 8 + srow) * 64 + scsw;
      else             src = Vst + ((size_t)(bh << 6) + i * 8 + srow) * NSP + s0 + scsw;
      gload16(src, kv + a * 4096 + i * 512 + lane * 8);
    }
  };

  int nmax = 0;
  #pragma unroll
  for (int jj = 3; jj <= 11; ++jj) nmax += (t0 + 64) >> jj;
  const int ntiles = (nmax + 63) >> 6;

  // ---- Phase 1: load Q tile f32, split to bf16 hi/lo, swizzled LDS ----
  {
    int row = tid >> 2;
    int d0  = (tid & 3) * 16;
    const float* qr = qkv + (size_t)(b * T_ + t0 + row) * QKV_LD + h * HS_ + d0;
    float qv[16];
    #pragma unroll
    for (int jj = 0; jj < 4; ++jj) {
      float4 v = *(const float4*)(qr + jj * 4);
      qv[jj*4+0] = v.x; qv[jj*4+1] = v.y; qv[jj*4+2] = v.z; qv[jj*4+3] = v.w;
    }
    short8 hh[2], ll[2];
    #pragma unroll
    for (int c = 0; c < 2; ++c)
      #pragma unroll
      for (int jj = 0; jj < 8; ++jj) {
        float f = qv[c*8+jj];
        unsigned short hi = f2bf(f);
        hh[c][jj] = (short)hi;
        ll[c][jj] = (short)f2bf(f - bf2f(hi));
      }
    int swz = (row & 7) << 4;
    #pragma unroll
    for (int c = 0; c < 2; ++c) {
      int addr = (row * 128 + d0 * 2 + c * 16) ^ swz;
      *(short8*)((char*)Qh + addr) = hh[c];
      *(short8*)((char*)Ql + addr) = ll[c];
    }
    for (int s = tid; s < NSP; s += 256) rs_lds[s] = r_srt[s];
    stage_tile(&KV[0][0], 0);
  }
  __syncthreads();

  int rows[4];
  #pragma unroll
  for (int r = 0; r < 4; ++r) rows[r] = t0 + w * 16 + (lane >> 4) * 4 + r;

  f32x4 O[4];
  #pragma unroll
  for (int f = 0; f < 4; ++f) O[f] = (f32x4){0.f, 0.f, 0.f, 0.f};
  float mrun[4] = {NEGBIG, NEGBIG, NEGBIG, NEGBIG};
  float lsum[4] = {0.f, 0.f, 0.f, 0.f};

  const int arow  = w * 16 + col;
  const int aswz  = (arow & 7) << 4;
  const int kgrp  = (lane >> 4) * 8;
  int cur = 0;

  for (int tile = 0; tile < ntiles; ++tile) {
    const int s0 = tile * 64;
    if (tile + 1 < ntiles) stage_tile(&KV[cur ^ 1][0], s0 + 64);

    const char* kc = (const char*)&KV[cur][0];
    f32x4 S[4];
    #pragma unroll
    for (int f = 0; f < 4; ++f) S[f] = (f32x4){0.f, 0.f, 0.f, 0.f};

    #pragma unroll
    for (int ks = 0; ks < 2; ++ks) {
      int abyte = (arow * 128 + (kgrp + ks * 32) * 2) ^ aswz;
      short8 aH = *(const short8*)((const char*)Qh + abyte);
      short8 aL = *(const short8*)((const char*)Ql + abyte);
      int chnk = (lane >> 4) + ks * 4;
      #pragma unroll
      for (int f = 0; f < 4; ++f) {
        int so = f * 16 + col;
        int kb = so * 128 + ((chnk ^ (so & 7)) << 4);
        short8 bHv = *(const short8*)(kc + kb);
        short8 bLv = *(const short8*)(kc + 8192 + kb);
        S[f] = __builtin_amdgcn_mfma_f32_16x16x32_bf16(aH, bHv, S[f], 0, 0, 0);
        S[f] = __builtin_amdgcn_mfma_f32_16x16x32_bf16(aH, bLv, S[f], 0, 0, 0);
        S[f] = __builtin_amdgcn_mfma_f32_16x16x32_bf16(aL, bHv, S[f], 0, 0, 0);
      }
    }

    int rsv[4];
    #pragma unroll
    for (int f = 0; f < 4; ++f) rsv[f] = rs_lds[s0 + f * 16 + col];

    float zv[4][4];
    #pragma unroll
    for (int f = 0; f < 4; ++f)
      #pragma unroll
      for (int r = 0; r < 4; ++r)
        zv[f][r] = (rsv[f] > rows[r]) ? NEGBIG : S[f][r] * scale;

    // ---- fast-path check: all logits within mrun+8 ? ----
    float mx[4];
    #pragma unroll
    for (int r = 0; r < 4; ++r)
      mx[r] = fmaxf(fmaxf(zv[0][r], zv[1][r]), fmaxf(zv[2][r], zv[3][r]));
    int pred = (mx[0] <= mrun[0] + 8.f) & (mx[1] <= mrun[1] + 8.f) &
               (mx[2] <= mrun[2] + 8.f) & (mx[3] <= mrun[3] + 8.f);
    if (!__all(pred)) {
      #pragma unroll
      for (int r = 0; r < 4; ++r) {
        float mt = mx[r];
        mt = fmaxf(mt, __shfl_xor(mt, 1));
        mt = fmaxf(mt, __shfl_xor(mt, 2));
        mt = fmaxf(mt, __shfl_xor(mt, 4));
        mt = fmaxf(mt, __shfl_xor(mt, 8));
        float mv = fmaxf(mrun[r], mt);
        float fs = __expf(mrun[r] - mv);
        lsum[r] *= fs;
        #pragma unroll
        for (int f = 0; f < 4; ++f) O[f][r] *= fs;
        mrun[r] = mv;
      }
    }

    // ---- P = exp(z - mrun), masked; lane-local sum; write bf16 to LDS ----
    char* pw = (char*)Pl + w * 2048;
    #pragma unroll
    for (int r = 0; r < 4; ++r) {
      int rowr = (lane >> 4) * 4 + r;
      int rswz = (rowr & 7) << 4;
      #pragma unroll
      for (int f = 0; f < 4; ++f) {
        float p = __expf(zv[f][r] - mrun[r]);
        p = (rsv[f] > rows[r]) ? 0.f : p;
        lsum[r] += p;
        int addr = (rowr * 128 + (f * 16 + col) * 2) ^ rswz;
        *(unsigned short*)(pw + addr) = f2bf(p);
      }
    }

    #pragma unroll
    for (int ks = 0; ks < 2; ++ks) {
      int pbyte = (col * 128 + (kgrp + ks * 32) * 2) ^ ((col & 7) << 4);
      short8 pa = *(const short8*)(pw + pbyte);
      int chnk = (lane >> 4) + ks * 4;
      #pragma unroll
      for (int f = 0; f < 4; ++f) {
        int dr = f * 16 + col;
        short8 bv = *(const short8*)(kc + 16384 + dr * 128 + ((chnk ^ (dr & 7)) << 4));
        O[f] = __builtin_amdgcn_mfma_f32_16x16x32_bf16(pa, bv, O[f], 0, 0, 0);
      }
    }

    __syncthreads();   // drains next-tile gload16 + all waves done with cur
    cur ^= 1;
  }

  // ---- deferred cross-lane sum of lsum -> lrun ----
  float lrun[4];
  #pragma unroll
  for (int r = 0; r < 4; ++r) {
    float l = lsum[r];
    l += __shfl_xor(l, 1);
    l += __shfl_xor(l, 2);
    l += __shfl_xor(l, 4);
    l += __shfl_xor(l, 8);
    lrun[r] = l;
  }

  // ---- tail term: interval [t&~7, t] with q_phi, per-row VALU ----
  float ztail;
  {
    int trow = lane >> 2;
    int t = t0 + w * 16 + trow;
    int d0 = (lane & 3) * 16;
    const float* qr = qkv + (size_t)(b * T_ + t) * QKV_LD + h * HS_ + d0;
    float qv[16];
    #pragma unroll
    for (int jj = 0; jj < 4; ++jj) {
      float4 v = *(const float4*)(qr + jj * 4);
      qv[jj*4+0] = v.x; qv[jj*4+1] = v.y; qv[jj*4+2] = v.z; qv[jj*4+3] = v.w;
    }
    int lt = t & ~7;
    const float* kc1 = kcum + ((size_t)bh * T_ + t) * HS_ + d0;
    float kt[16];
    if (lt > 0) {
      const float* kc0 = kcum + ((size_t)bh * T_ + (lt - 1)) * HS_ + d0;
      #pragma unroll
      for (int jj = 0; jj < 16; ++jj) kt[jj] = kc1[jj] - kc0[jj];
    } else {
      #pragma unroll
      for (int jj = 0; jj < 16; ++jj) kt[jj] = kc1[jj];
    }
    float z = 0.f;
    #pragma unroll
    for (int jj = 0; jj < 16; ++jj) {
      float qp = qv[jj] > 0.f ? qv[jj] + 1.f : __expf(qv[jj]);
      z += qp * kt[jj];
    }
    z += __shfl_xor(z, 1);
    z += __shfl_xor(z, 2);
    ztail = z * scale;
  }

  #pragma unroll
  for (int r = 0; r < 4; ++r) {
    float zt = __shfl(ztail, ((lane >> 4) * 4 + r) * 4);
    float mv = fmaxf(mrun[r], zt);
    float fs = __expf(mrun[r] - mv);           // mrun=NEGBIG -> 0
    float pwgt = __expf(zt - mv);
    lrun[r] = lrun[r] * fs + pwgt;
    int tr = rows[r];
    int ltr = tr & ~7;
    #pragma unroll
    for (int f = 0; f < 4; ++f) {
      int d = f * 16 + col;
      float v1 = vcum[((size_t)bh * T_ + tr) * HS_ + d];
      float vt = (ltr > 0) ? v1 - vcum[((size_t)bh * T_ + (ltr - 1)) * HS_ + d] : v1;
      O[f][r] = O[f][r] * fs + pwgt * vt;
    }
  }

  #pragma unroll
  for (int r = 0; r < 4; ++r) {
    float inv = 1.f / lrun[r];
    unsigned short* orow = attnb + (size_t)(b * T_ + rows[r]) * CD + h * HS_;
    #pragma unroll
    for (int f = 0; f < 4; ++f)
      orow[f * 16 + col] = f2bf(O[f][r] * inv);
  }
}

// --------------------------------------------------------------------------
extern "C" void kernel_launch(void* const* d_in, const int* in_sizes, int n_in,
                              void* d_out, int out_size, void* d_ws, size_t ws_size,
                              hipStream_t stream) {
  const float* x  = (const float*)d_in[0];   // [B,T,C]
  const float* Wa = (const float*)d_in[1];   // [3C,C]
  const float* Wp = (const float*)d_in[2];   // [C,C]
  float* out = (float*)d_out;                // [B,T,C]

  char* ws = (char*)d_ws;
  size_t off = 0;
  auto alloc = [&](size_t bytes) -> char* {
    char* p = ws + off;
    off += (bytes + 255) & ~(size_t)255;
    return p;
  };

  const int M = B_ * T_;                     // 4096
  float* qkv  = (float*)alloc((size_t)M * QKV_LD * 4);            // 50.3 MB
  float* kcum = (float*)alloc((size_t)B_ * NH_ * T_ * HS_ * 4);   // 16.8 MB
  float* vcum = (float*)alloc((size_t)B_ * NH_ * T_ * HS_ * 4);   // 16.8 MB
  float* part = (float*)alloc((size_t)B_ * 32 * 2048 * 4);        // 0.5 MB
  unsigned short* wph = (unsigned short*)alloc((size_t)CD * CD * 2);

  // regionA: x_hi/x_lo (live through gemm1), then sorted set arrays
  char* regionA = alloc((size_t)16777216);
  unsigned short* xh = (unsigned short*)regionA;
  unsigned short* xl = (unsigned short*)(regionA + (size_t)M * CD * 2);
  const size_t SETS_ELEMS = (size_t)B_ * NH_ * NSP * HS_;          // 2M
  unsigned short* Ksh = (unsigned short*)regionA;                  // 4 MB
  unsigned short* Ksl = Ksh + SETS_ELEMS;                          // 4 MB
  float*          Vss = (float*)(regionA + 2 * SETS_ELEMS * 2);    // 8 MB
  unsigned short* Vst = (unsigned short*)(regionA + 2 * SETS_ELEMS * 2 + SETS_ELEMS * 4);
  int*            r_srt = (int*)(regionA + 2 * SETS_ELEMS * 2 + SETS_ELEMS * 4 + SETS_ELEMS * 2);

  // regionB: Wa_hi/Wa_lo (live through gemm1), then attn bf16 output
  char* regionB = alloc((size_t)12582912);
  unsigned short* wah = (unsigned short*)regionB;
  unsigned short* wal = (unsigned short*)(regionB + (size_t)3 * CD * CD * 2);
  unsigned short* attnb = (unsigned short*)regionB;

  // K1: fused splits
  split3_kernel<<<dim3(32768), dim3(256), 0, stream>>>(
      x, Wa, Wp, xh, xl, wah, wal, wph);

  // K2: qkv = x @ Wa^T  (split-bf16, ~f32 precision)
  gemm_bt<1><<<dim3((QKV_LD / 128) * (M / 128)), dim3(256), 0, stream>>>(
      xh, xl, wah, wal, qkv, M, QKV_LD, CD);

  // K3: phi + cumsums (coalesced 3-phase)
  cs_part<<<dim3(B_ * 32 * 2), dim3(256), 0, stream>>>(qkv, part);
  cs_prefix<<<dim3(B_ * 2048 / 256), dim3(256), 0, stream>>>(part);
  cs_final<<<dim3(B_ * 32 * 2), dim3(256), 0, stream>>>(qkv, part, kcum, vcum);

  // K4: sorted set aggregates (reuses regionA — xh/xl dead after gemm1)
  build_sets<<<dim3((B_ * NH_ * NSP * HS_) / 256), dim3(256), 0, stream>>>(
      kcum, vcum, Ksh, Ksl, Vss, r_srt);
  vst_transpose<<<dim3(B_ * NH_ * (NSP / 64)), dim3(256), 0, stream>>>(Vss, Vst);

  // K5: MFMA attention (writes bf16 into regionB — wah/wal dead after gemm1)
  attn_mfma<<<dim3(B_ * NH_ * (T_ / 64)), dim3(256), 0, stream>>>(
      qkv, kcum, vcum, Ksh, Ksl, Vst, r_srt, attnb);

  // K7: out = attn @ Wp^T
  gemm_bt<0><<<dim3((CD / 128) * (M / 128)), dim3(256), 0, stream>>>(
      attnb, (const unsigned short*)nullptr, wph, (const unsigned short*)nullptr,
      out, M, CD, CD);
}

// Round 6
// 223.841 us; speedup vs baseline: 4.9173x; 1.0215x over previous
//
#include <hip/hip_runtime.h>
#include <hip/hip_bf16.h>
#include <stdint.h>

// Problem constants (B,T,C,NH,LEVEL) = (2,2048,1024,16,3)
#define B_    2
#define T_    2048
#define CD    1024
#define NH_   16
#define HS_   64
#define NSETS 511        // sum_{l=3..11} 2048>>l
#define NSP   512        // padded
#define QKV_LD 3072
#define NEGBIG (-3.4e38f)

typedef __attribute__((ext_vector_type(8))) short  short8;
typedef __attribute__((ext_vector_type(4))) float  f32x4;

__device__ __forceinline__ unsigned short f2bf(float f) {
  unsigned u = __float_as_uint(f);
  unsigned r = 0x7FFFu + ((u >> 16) & 1u);   // round-to-nearest-even
  return (unsigned short)((u + r) >> 16);
}
__device__ __forceinline__ float bf2f(unsigned short h) {
  return __uint_as_float(((unsigned)h) << 16);
}
__device__ __forceinline__ float elu1(float x) {  // elu(x)+1
  return x > 0.f ? x + 1.f : __expf(x);
}
__device__ __forceinline__ void gload16(const unsigned short* g, short* l) {
  __builtin_amdgcn_global_load_lds(
      (const __attribute__((address_space(1))) unsigned int*)g,
      (__attribute__((address_space(3))) unsigned int*)l, 16, 0, 0);
}

// ---------------- K1: fused splits -----------------------------------------
// x -> hi/lo; Wa rows 0..2047 (q,k) -> hi/lo; Wa rows 2048.. (v) -> hi only;
// Wp -> hi only.
__global__ __launch_bounds__(256) void split3_kernel(
    const float* __restrict__ x, const float* __restrict__ Wa,
    const float* __restrict__ Wp,
    unsigned short* __restrict__ xh, unsigned short* __restrict__ xl,
    unsigned short* __restrict__ wah, unsigned short* __restrict__ wal,
    unsigned short* __restrict__ wph) {
  int bid = blockIdx.x;
  const float* src; unsigned short *hi, *lo; int base;
  if (bid < 16384)      { src = x;  hi = xh;  lo = xl;  base = bid; }
  else if (bid < 24576) { src = Wa; hi = wah; lo = wal; base = bid - 16384; }
  else if (bid < 28672) { src = Wa; hi = wah; lo = nullptr; base = bid - 16384; }
  else                  { src = Wp; hi = wph; lo = nullptr; base = bid - 28672; }
  int i = base * 256 + threadIdx.x;
  float v = src[i];
  unsigned short h = f2bf(v);
  hi[i] = h;
  if (lo) lo[i] = f2bf(v - bf2f(h));
}

// ---------------- K2/K7: C[M,N] = A[M,K] * B[N,K]^T  (bf16 MFMA) ----------
// m97 structure: global_load_lds width=16 staging, 2-barrier K-loop.
// ldc = row stride of C (allows writing column slices of qkv).
template<int SPLIT>
__global__ __launch_bounds__(256) void gemm_bt(
    const unsigned short* __restrict__ Ah, const unsigned short* __restrict__ Al,
    const unsigned short* __restrict__ Bh, const unsigned short* __restrict__ Bl,
    float* __restrict__ Cmat, int M, int N, int K, int ldc)
{
  constexpr int NT = SPLIT ? 4 : 2;
  __shared__ short lds[NT * 4096];                   // 8KB per tile

  // XCD-aware bijective swizzle (grid %8 == 0 for all instantiations)
  const int nwg = gridDim.x;
  const int cpx = nwg >> 3;
  const int bid = blockIdx.x;
  const int swb = (bid & 7) * cpx + (bid >> 3);
  const int nbx = N >> 7;
  const int bx = swb % nbx;
  const int by = swb / nbx;

  const int row0 = by * 128;
  const int col0 = bx * 128;
  const int tid  = threadIdx.x;
  const int lane = tid & 63;
  const int w    = tid >> 6;
  const int wr   = w >> 1, wc = w & 1;

  f32x4 acc[4][4];
  #pragma unroll
  for (int a = 0; a < 4; ++a)
    #pragma unroll
    for (int b = 0; b < 4; ++b)
      acc[a][b] = (f32x4){0.f, 0.f, 0.f, 0.f};

  const int rlane = lane & 15;
  const int kgrp  = lane >> 4;                       // 0..3 (16B chunk)
  const int rsw   = (kgrp ^ (rlane & 3) ^ ((rlane >> 2) & 3)) << 4;

  // staging: lane l -> row l>>2, chunk l&3 (linear LDS dest)
  const int slr = lane >> 2;                         // row within 16-row block
  const int sch = (lane & 3) ^ (slr & 3) ^ ((slr >> 2) & 3);

  const unsigned short* ssrc;
  size_t srb;
  short* sbase;
  if (SPLIT) {
    ssrc = (w == 0) ? Ah : (w == 1) ? Bh : (w == 2) ? Al : Bl;
    srb  = (w & 1) ? (size_t)col0 : (size_t)row0;
    sbase = &lds[w * 4096];
  } else {
    ssrc = (w & 1) ? Bh : Ah;
    srb  = (w & 1) ? (size_t)col0 : (size_t)row0;
    sbase = &lds[(w & 1) * 4096 + (w >> 1) * 2048];  // half-tile per wave
    srb += (size_t)(w >> 1) * 64;
  }

  for (int kt = 0; kt < K; kt += 32) {
    __syncthreads();
    const unsigned short* g0 = ssrc + (srb + slr) * K + kt + (sch << 3);
    if (SPLIT) {
      #pragma unroll
      for (int i = 0; i < 8; ++i)
        gload16(g0 + (size_t)i * 16 * K, sbase + i * 512);
    } else {
      #pragma unroll
      for (int i = 0; i < 4; ++i)
        gload16(g0 + (size_t)i * 16 * K, sbase + i * 512);
    }
    __syncthreads();   // compiler drains vmcnt(0) here

    short8 aH[4], bH[4], aL[4], bL[4];
    #pragma unroll
    for (int m = 0; m < 4; ++m) {
      int r    = wr * 64 + m * 16 + rlane;
      int cidx = wc * 64 + m * 16 + rlane;
      aH[m] = *(const short8*)((const char*)lds + r * 64 + rsw);
      bH[m] = *(const short8*)((const char*)lds + 8192 + cidx * 64 + rsw);
      if (SPLIT) {
        aL[m] = *(const short8*)((const char*)lds + 16384 + r * 64 + rsw);
        bL[m] = *(const short8*)((const char*)lds + 24576 + cidx * 64 + rsw);
      }
    }
    #pragma unroll
    for (int mm = 0; mm < 4; ++mm)
      #pragma unroll
      for (int nn = 0; nn < 4; ++nn) {
        acc[mm][nn] = __builtin_amdgcn_mfma_f32_16x16x32_bf16(aH[mm], bH[nn], acc[mm][nn], 0, 0, 0);
        if (SPLIT) {
          acc[mm][nn] = __builtin_amdgcn_mfma_f32_16x16x32_bf16(aH[mm], bL[nn], acc[mm][nn], 0, 0, 0);
          acc[mm][nn] = __builtin_amdgcn_mfma_f32_16x16x32_bf16(aL[mm], bH[nn], acc[mm][nn], 0, 0, 0);
        }
      }
  }

  const int rl = (lane >> 4) * 4;
  const int cl = lane & 15;
  #pragma unroll
  for (int mm = 0; mm < 4; ++mm)
    #pragma unroll
    for (int nn = 0; nn < 4; ++nn)
      #pragma unroll
      for (int r = 0; r < 4; ++r) {
        int row = row0 + wr * 64 + mm * 16 + rl + r;
        int col = col0 + wc * 64 + nn * 16 + cl;
        Cmat[(size_t)row * ldc + col] = acc[mm][nn][r];
      }
}

// ---------------- K3a: per-seg partial sums (coalesced float4 columns) ----
__global__ __launch_bounds__(256) void cs_part(const float* __restrict__ qkv,
                                               float* __restrict__ part) {
  int blk = blockIdx.x;                 // B*32*2
  int q   = blk & 1;
  int seg = (blk >> 1) & 31;
  int b   = blk >> 6;
  int c   = threadIdx.x * 4;            // 0..1023
  const float* src = qkv + (size_t)(b * T_ + seg * 64) * QKV_LD + CD + q * CD + c;
  float4 s = {0.f, 0.f, 0.f, 0.f};
  #pragma unroll 4
  for (int j = 0; j < 64; ++j) {
    float4 v = *(const float4*)(src + (size_t)j * QKV_LD);
    if (q == 0) {
      s.x += elu1(v.x); s.y += elu1(v.y); s.z += elu1(v.z); s.w += elu1(v.w);
    } else {
      s.x += v.x; s.y += v.y; s.z += v.z; s.w += v.w;
    }
  }
  *(float4*)(part + ((size_t)(b * 32 + seg) * 2048) + q * 1024 + c) = s;
}

// ---------------- K3b: exclusive prefix over 32 segs per column ----------
__global__ void cs_prefix(float* __restrict__ part) {
  int idx = blockIdx.x * 256 + threadIdx.x;      // B*2048
  int b  = idx >> 11;
  int cc = idx & 2047;
  float run = 0.f;
  #pragma unroll 8
  for (int s = 0; s < 32; ++s) {
    size_t o = (size_t)(b * 32 + s) * 2048 + cc;
    float t = part[o];
    part[o] = run;
    run += t;
  }
}

// ---------------- K3c: final walk -> kcum / vcum --------------------------
__global__ __launch_bounds__(256) void cs_final(const float* __restrict__ qkv,
                                                const float* __restrict__ part,
                                                float* __restrict__ kcum,
                                                float* __restrict__ vcum) {
  int blk = blockIdx.x;
  int q   = blk & 1;
  int seg = (blk >> 1) & 31;
  int b   = blk >> 6;
  int c   = threadIdx.x * 4;
  int h   = c >> 6, d = c & 63;
  const float* src = qkv + (size_t)(b * T_ + seg * 64) * QKV_LD + CD + q * CD + c;
  float* dst = (q == 0 ? kcum : vcum) + ((size_t)(b * NH_ + h) * T_ + seg * 64) * HS_ + d;
  float4 s = *(const float4*)(part + ((size_t)(b * 32 + seg) * 2048) + q * 1024 + c);
  #pragma unroll 4
  for (int j = 0; j < 64; ++j) {
    float4 v = *(const float4*)(src + (size_t)j * QKV_LD);
    if (q == 0) {
      s.x += elu1(v.x); s.y += elu1(v.y); s.z += elu1(v.z); s.w += elu1(v.w);
    } else {
      s.x += v.x; s.y += v.y; s.z += v.z; s.w += v.w;
    }
    *(float4*)(dst + (size_t)j * HS_) = s;
  }
}

// ---------------- K4: sorted-by-r set aggregates ---------------------------
__global__ void build_sets(const float* __restrict__ kcum, const float* __restrict__ vcum,
                           unsigned short* __restrict__ Ksh, unsigned short* __restrict__ Ksl,
                           float* __restrict__ Vs, int* __restrict__ r_srt) {
  int idx = blockIdx.x * 256 + threadIdx.x;    // B*NH*512*64
  if (idx >= B_ * NH_ * NSP * HS_) return;
  int d  = idx & 63;
  int s  = (idx >> 6) & (NSP - 1);
  int bh = idx >> (6 + 9);
  if (s == NSETS) {                            // padding entry
    size_t o = ((size_t)(bh << 9) + s) * HS_ + d;
    Ksh[o] = 0; Ksl[o] = 0; Vs[o] = 0.f;
    if (bh == 0 && d == 0) r_srt[s] = 0x7fffffff;
    return;
  }
  int lvl = 3, base = 0;
  while (s >= base + (T_ >> lvl)) { base += T_ >> lvl; ++lvl; }
  int i  = s - base;
  int m  = (i + 1) << lvl;
  int r  = m - 1;
  int li = i << lvl;
  int rank = lvl - 3;
  #pragma unroll
  for (int j = 3; j <= 11; ++j) rank += (m - 8) >> j;

  size_t rowr = ((size_t)bh * T_ + r) * HS_ + d;
  float kr = kcum[rowr], vr = vcum[rowr];
  if (li > 0) {
    size_t rowl = ((size_t)bh * T_ + li - 1) * HS_ + d;
    kr -= kcum[rowl];
    vr -= vcum[rowl];
  }
  size_t o = ((size_t)(bh << 9) + rank) * HS_ + d;
  unsigned short kh = f2bf(kr);
  Ksh[o] = kh;
  Ksl[o] = f2bf(kr - bf2f(kh));
  Vs[o]  = vr;
  if (bh == 0 && d == 0) r_srt[rank] = r;
}

// ---------------- K4b: Vst[bh][d][512] bf16 = transpose(Vs) ---------------
__global__ __launch_bounds__(256) void vst_transpose(
    const float* __restrict__ Vs, unsigned short* __restrict__ Vst) {
  __shared__ float tile[64][65];
  int bh = blockIdx.x >> 3;
  int s0 = (blockIdx.x & 7) * 64;
  int tid = threadIdx.x;
  int srow = tid >> 2, c0 = (tid & 3) * 16;
  const float* src = Vs + ((size_t)(bh << 9) + s0 + srow) * HS_ + c0;
  #pragma unroll
  for (int j = 0; j < 4; ++j) {
    float4 v = *(const float4*)(src + j * 4);
    tile[srow][c0 + j*4 + 0] = v.x; tile[srow][c0 + j*4 + 1] = v.y;
    tile[srow][c0 + j*4 + 2] = v.z; tile[srow][c0 + j*4 + 3] = v.w;
  }
  __syncthreads();
  int d = tid >> 2, sq = (tid & 3) * 16;
  short8 a, b;
  #pragma unroll
  for (int j = 0; j < 8; ++j) {
    a[j] = (short)f2bf(tile[sq + j][d]);
    b[j] = (short)f2bf(tile[sq + 8 + j][d]);
  }
  unsigned short* dst = Vst + ((size_t)(bh << 6) + d) * NSP + s0 + sq;
  *(short8*)dst = a;
  *(short8*)(dst + 8) = b;
}

// ---------------- K5: MFMA flash attention over sorted sets ---------------
// Single-buffered K/V LDS staging (50KB total -> 3 blocks/CU); cross-block
// wave overlap hides the per-tile stage latency (m114 mechanism).
// Defer-max softmax (THR=8), deferred cross-lane sum.
__global__ __launch_bounds__(256) void attn_mfma(
    const float* __restrict__ qkv, const float* __restrict__ kcum,
    const float* __restrict__ vcum,
    const unsigned short* __restrict__ Ksh, const unsigned short* __restrict__ Ksl,
    const unsigned short* __restrict__ Vst, const int* __restrict__ r_srt,
    unsigned short* __restrict__ attnb)
{
  __shared__ short Qh[64 * 64];
  __shared__ short Ql[64 * 64];
  __shared__ short Pl[4 * 16 * 64];
  __shared__ short KV[3 * 4096];        // Ksh|Ksl|Vst tiles, 8KB each
  __shared__ int   rs_lds[NSP];

  const int blk = blockIdx.x;           // 1024
  const int xcd = blk & 7;
  const int j   = blk >> 3;             // 0..127
  const int bh  = xcd * 4 + (j >> 5);
  const int tch = (j + ((j >> 5) << 3)) & 31;
  const int b = bh >> 4, h = bh & 15;
  const int t0 = tch * 64;
  const int tid = threadIdx.x;
  const int lane = tid & 63;
  const int w = tid >> 6;
  const int col = lane & 15;
  const float scale = 0.125f;

  // staging geometry: per wave 6 gload16; lane l -> row i*8+(l>>3),
  // pre-swizzled source chunk ((l&7)^(l>>3)); LDS dest linear (lane*16B)
  const int srow = lane >> 3;
  const int scsw = ((lane & 7) ^ srow) * 8;

  auto stage_tile = [&](short* kv, int s0) {
    #pragma unroll
    for (int L = w * 6; L < w * 6 + 6; ++L) {
      int a = L >> 3, i = L & 7;
      const unsigned short* src;
      if (a == 0)      src = Ksh + ((size_t)(bh << 9) + s0 + i * 8 + srow) * 64 + scsw;
      else if (a == 1) src = Ksl + ((size_t)(bh << 9) + s0 + i * 8 + srow) * 64 + scsw;
      else             src = Vst + ((size_t)(bh << 6) + i * 8 + srow) * NSP + s0 + scsw;
      gload16(src, kv + a * 4096 + i * 512 + lane * 8);
    }
  };

  int nmax = 0;
  #pragma unroll
  for (int jj = 3; jj <= 11; ++jj) nmax += (t0 + 64) >> jj;
  const int ntiles = (nmax + 63) >> 6;

  // ---- Phase 1: load Q tile f32, split to bf16 hi/lo, swizzled LDS ----
  {
    int row = tid >> 2;
    int d0  = (tid & 3) * 16;
    const float* qr = qkv + (size_t)(b * T_ + t0 + row) * QKV_LD + h * HS_ + d0;
    float qv[16];
    #pragma unroll
    for (int jj = 0; jj < 4; ++jj) {
      float4 v = *(const float4*)(qr + jj * 4);
      qv[jj*4+0] = v.x; qv[jj*4+1] = v.y; qv[jj*4+2] = v.z; qv[jj*4+3] = v.w;
    }
    short8 hh[2], ll[2];
    #pragma unroll
    for (int c = 0; c < 2; ++c)
      #pragma unroll
      for (int jj = 0; jj < 8; ++jj) {
        float f = qv[c*8+jj];
        unsigned short hi = f2bf(f);
        hh[c][jj] = (short)hi;
        ll[c][jj] = (short)f2bf(f - bf2f(hi));
      }
    int swz = (row & 7) << 4;
    #pragma unroll
    for (int c = 0; c < 2; ++c) {
      int addr = (row * 128 + d0 * 2 + c * 16) ^ swz;
      *(short8*)((char*)Qh + addr) = hh[c];
      *(short8*)((char*)Ql + addr) = ll[c];
    }
    for (int s = tid; s < NSP; s += 256) rs_lds[s] = r_srt[s];
  }

  int rows[4];
  #pragma unroll
  for (int r = 0; r < 4; ++r) rows[r] = t0 + w * 16 + (lane >> 4) * 4 + r;

  f32x4 O[4];
  #pragma unroll
  for (int f = 0; f < 4; ++f) O[f] = (f32x4){0.f, 0.f, 0.f, 0.f};
  float mrun[4] = {NEGBIG, NEGBIG, NEGBIG, NEGBIG};
  float lsum[4] = {0.f, 0.f, 0.f, 0.f};

  const int arow  = w * 16 + col;
  const int aswz  = (arow & 7) << 4;
  const int kgrp  = (lane >> 4) * 8;

  for (int tile = 0; tile < ntiles; ++tile) {
    const int s0 = tile * 64;
    stage_tile(KV, s0);
    __syncthreads();       // drains gload vmcnt(0); also covers Phase-1 LDS

    const char* kc = (const char*)KV;
    f32x4 S[4];
    #pragma unroll
    for (int f = 0; f < 4; ++f) S[f] = (f32x4){0.f, 0.f, 0.f, 0.f};

    #pragma unroll
    for (int ks = 0; ks < 2; ++ks) {
      int abyte = (arow * 128 + (kgrp + ks * 32) * 2) ^ aswz;
      short8 aH = *(const short8*)((const char*)Qh + abyte);
      short8 aL = *(const short8*)((const char*)Ql + abyte);
      int chnk = (lane >> 4) + ks * 4;
      #pragma unroll
      for (int f = 0; f < 4; ++f) {
        int so = f * 16 + col;
        int kb = so * 128 + ((chnk ^ (so & 7)) << 4);
        short8 bHv = *(const short8*)(kc + kb);
        short8 bLv = *(const short8*)(kc + 8192 + kb);
        S[f] = __builtin_amdgcn_mfma_f32_16x16x32_bf16(aH, bHv, S[f], 0, 0, 0);
        S[f] = __builtin_amdgcn_mfma_f32_16x16x32_bf16(aH, bLv, S[f], 0, 0, 0);
        S[f] = __builtin_amdgcn_mfma_f32_16x16x32_bf16(aL, bHv, S[f], 0, 0, 0);
      }
    }

    int rsv[4];
    #pragma unroll
    for (int f = 0; f < 4; ++f) rsv[f] = rs_lds[s0 + f * 16 + col];

    float zv[4][4];
    #pragma unroll
    for (int f = 0; f < 4; ++f)
      #pragma unroll
      for (int r = 0; r < 4; ++r)
        zv[f][r] = (rsv[f] > rows[r]) ? NEGBIG : S[f][r] * scale;

    // ---- fast-path check: all logits within mrun+8 ? ----
    float mx[4];
    #pragma unroll
    for (int r = 0; r < 4; ++r)
      mx[r] = fmaxf(fmaxf(zv[0][r], zv[1][r]), fmaxf(zv[2][r], zv[3][r]));
    int pred = (mx[0] <= mrun[0] + 8.f) & (mx[1] <= mrun[1] + 8.f) &
               (mx[2] <= mrun[2] + 8.f) & (mx[3] <= mrun[3] + 8.f);
    if (!__all(pred)) {
      #pragma unroll
      for (int r = 0; r < 4; ++r) {
        float mt = mx[r];
        mt = fmaxf(mt, __shfl_xor(mt, 1));
        mt = fmaxf(mt, __shfl_xor(mt, 2));
        mt = fmaxf(mt, __shfl_xor(mt, 4));
        mt = fmaxf(mt, __shfl_xor(mt, 8));
        float mv = fmaxf(mrun[r], mt);
        float fs = __expf(mrun[r] - mv);
        lsum[r] *= fs;
        #pragma unroll
        for (int f = 0; f < 4; ++f) O[f][r] *= fs;
        mrun[r] = mv;
      }
    }

    // ---- P = exp(z - mrun), masked; lane-local sum; write bf16 to LDS ----
    char* pw = (char*)Pl + w * 2048;
    #pragma unroll
    for (int r = 0; r < 4; ++r) {
      int rowr = (lane >> 4) * 4 + r;
      int rswz = (rowr & 7) << 4;
      #pragma unroll
      for (int f = 0; f < 4; ++f) {
        float p = __expf(zv[f][r] - mrun[r]);
        p = (rsv[f] > rows[r]) ? 0.f : p;
        lsum[r] += p;
        int addr = (rowr * 128 + (f * 16 + col) * 2) ^ rswz;
        *(unsigned short*)(pw + addr) = f2bf(p);
      }
    }

    #pragma unroll
    for (int ks = 0; ks < 2; ++ks) {
      int pbyte = (col * 128 + (kgrp + ks * 32) * 2) ^ ((col & 7) << 4);
      short8 pa = *(const short8*)(pw + pbyte);
      int chnk = (lane >> 4) + ks * 4;
      #pragma unroll
      for (int f = 0; f < 4; ++f) {
        int dr = f * 16 + col;
        short8 bv = *(const short8*)(kc + 16384 + dr * 128 + ((chnk ^ (dr & 7)) << 4));
        O[f] = __builtin_amdgcn_mfma_f32_16x16x32_bf16(pa, bv, O[f], 0, 0, 0);
      }
    }

    __syncthreads();       // all waves done reading KV before next stage
  }

  // ---- deferred cross-lane sum of lsum -> lrun ----
  float lrun[4];
  #pragma unroll
  for (int r = 0; r < 4; ++r) {
    float l = lsum[r];
    l += __shfl_xor(l, 1);
    l += __shfl_xor(l, 2);
    l += __shfl_xor(l, 4);
    l += __shfl_xor(l, 8);
    lrun[r] = l;
  }

  // ---- tail term: interval [t&~7, t] with q_phi, per-row VALU ----
  float ztail;
  {
    int trow = lane >> 2;
    int t = t0 + w * 16 + trow;
    int d0 = (lane & 3) * 16;
    const float* qr = qkv + (size_t)(b * T_ + t) * QKV_LD + h * HS_ + d0;
    float qv[16];
    #pragma unroll
    for (int jj = 0; jj < 4; ++jj) {
      float4 v = *(const float4*)(qr + jj * 4);
      qv[jj*4+0] = v.x; qv[jj*4+1] = v.y; qv[jj*4+2] = v.z; qv[jj*4+3] = v.w;
    }
    int lt = t & ~7;
    const float* kc1 = kcum + ((size_t)bh * T_ + t) * HS_ + d0;
    float kt[16];
    if (lt > 0) {
      const float* kc0 = kcum + ((size_t)bh * T_ + (lt - 1)) * HS_ + d0;
      #pragma unroll
      for (int jj = 0; jj < 16; ++jj) kt[jj] = kc1[jj] - kc0[jj];
    } else {
      #pragma unroll
      for (int jj = 0; jj < 16; ++jj) kt[jj] = kc1[jj];
    }
    float z = 0.f;
    #pragma unroll
    for (int jj = 0; jj < 16; ++jj) {
      float qp = qv[jj] > 0.f ? qv[jj] + 1.f : __expf(qv[jj]);
      z += qp * kt[jj];
    }
    z += __shfl_xor(z, 1);
    z += __shfl_xor(z, 2);
    ztail = z * scale;
  }

  #pragma unroll
  for (int r = 0; r < 4; ++r) {
    float zt = __shfl(ztail, ((lane >> 4) * 4 + r) * 4);
    float mv = fmaxf(mrun[r], zt);
    float fs = __expf(mrun[r] - mv);           // mrun=NEGBIG -> 0
    float pwgt = __expf(zt - mv);
    lrun[r] = lrun[r] * fs + pwgt;
    int tr = rows[r];
    int ltr = tr & ~7;
    #pragma unroll
    for (int f = 0; f < 4; ++f) {
      int d = f * 16 + col;
      float v1 = vcum[((size_t)bh * T_ + tr) * HS_ + d];
      float vt = (ltr > 0) ? v1 - vcum[((size_t)bh * T_ + (ltr - 1)) * HS_ + d] : v1;
      O[f][r] = O[f][r] * fs + pwgt * vt;
    }
  }

  #pragma unroll
  for (int r = 0; r < 4; ++r) {
    float inv = 1.f / lrun[r];
    unsigned short* orow = attnb + (size_t)(b * T_ + rows[r]) * CD + h * HS_;
    #pragma unroll
    for (int f = 0; f < 4; ++f)
      orow[f * 16 + col] = f2bf(O[f][r] * inv);
  }
}

// --------------------------------------------------------------------------
extern "C" void kernel_launch(void* const* d_in, const int* in_sizes, int n_in,
                              void* d_out, int out_size, void* d_ws, size_t ws_size,
                              hipStream_t stream) {
  const float* x  = (const float*)d_in[0];   // [B,T,C]
  const float* Wa = (const float*)d_in[1];   // [3C,C]
  const float* Wp = (const float*)d_in[2];   // [C,C]
  float* out = (float*)d_out;                // [B,T,C]

  char* ws = (char*)d_ws;
  size_t off = 0;
  auto alloc = [&](size_t bytes) -> char* {
    char* p = ws + off;
    off += (bytes + 255) & ~(size_t)255;
    return p;
  };

  const int M = B_ * T_;                     // 4096
  float* qkv  = (float*)alloc((size_t)M * QKV_LD * 4);            // 50.3 MB
  float* kcum = (float*)alloc((size_t)B_ * NH_ * T_ * HS_ * 4);   // 16.8 MB
  float* vcum = (float*)alloc((size_t)B_ * NH_ * T_ * HS_ * 4);   // 16.8 MB
  float* part = (float*)alloc((size_t)B_ * 32 * 2048 * 4);        // 0.5 MB
  unsigned short* wph = (unsigned short*)alloc((size_t)CD * CD * 2);

  // regionA: x_hi/x_lo (live through gemm1), then sorted set arrays
  char* regionA = alloc((size_t)16777216);
  unsigned short* xh = (unsigned short*)regionA;
  unsigned short* xl = (unsigned short*)(regionA + (size_t)M * CD * 2);
  const size_t SETS_ELEMS = (size_t)B_ * NH_ * NSP * HS_;          // 2M
  unsigned short* Ksh = (unsigned short*)regionA;                  // 4 MB
  unsigned short* Ksl = Ksh + SETS_ELEMS;                          // 4 MB
  float*          Vss = (float*)(regionA + 2 * SETS_ELEMS * 2);    // 8 MB
  unsigned short* Vst = (unsigned short*)(regionA + 2 * SETS_ELEMS * 2 + SETS_ELEMS * 4);
  int*            r_srt = (int*)(regionA + 2 * SETS_ELEMS * 2 + SETS_ELEMS * 4 + SETS_ELEMS * 2);

  // regionB: Wa_hi/Wa_lo (live through gemm1), then attn bf16 output
  char* regionB = alloc((size_t)12582912);
  unsigned short* wah = (unsigned short*)regionB;
  unsigned short* wal = (unsigned short*)(regionB + (size_t)3 * CD * CD * 2);
  unsigned short* attnb = (unsigned short*)regionB;

  // K1: fused splits (Wa v-rows get hi only)
  split3_kernel<<<dim3(32768), dim3(256), 0, stream>>>(
      x, Wa, Wp, xh, xl, wah, wal, wph);

  // K2a: q,k = x @ Wa[0:2048]^T  (split-bf16, ~f32 precision)
  gemm_bt<1><<<dim3((2048 / 128) * (M / 128)), dim3(256), 0, stream>>>(
      xh, xl, wah, wal, qkv, M, 2048, CD, QKV_LD);

  // K2b: v = x @ Wa[2048:3072]^T  (plain bf16 — linear error path)
  gemm_bt<0><<<dim3((1024 / 128) * (M / 128)), dim3(256), 0, stream>>>(
      xh, (const unsigned short*)nullptr, wah + (size_t)2048 * CD,
      (const unsigned short*)nullptr, qkv + 2048, M, 1024, CD, QKV_LD);

  // K3: phi + cumsums (coalesced 3-phase)
  cs_part<<<dim3(B_ * 32 * 2), dim3(256), 0, stream>>>(qkv, part);
  cs_prefix<<<dim3(B_ * 2048 / 256), dim3(256), 0, stream>>>(part);
  cs_final<<<dim3(B_ * 32 * 2), dim3(256), 0, stream>>>(qkv, part, kcum, vcum);

  // K4: sorted set aggregates (reuses regionA — xh/xl dead after gemm1)
  build_sets<<<dim3((B_ * NH_ * NSP * HS_) / 256), dim3(256), 0, stream>>>(
      kcum, vcum, Ksh, Ksl, Vss, r_srt);
  vst_transpose<<<dim3(B_ * NH_ * (NSP / 64)), dim3(256), 0, stream>>>(Vss, Vst);

  // K5: MFMA attention (writes bf16 into regionB — wah/wal dead after gemm1)
  attn_mfma<<<dim3(B_ * NH_ * (T_ / 64)), dim3(256), 0, stream>>>(
      qkv, kcum, vcum, Ksh, Ksl, Vst, r_srt, attnb);

  // K7: out = attn @ Wp^T
  gemm_bt<0><<<dim3((CD / 128) * (M / 128)), dim3(256), 0, stream>>>(
      attnb, (const unsigned short*)nullptr, wph, (const unsigned short*)nullptr,
      out, M, CD, CD, CD);
}